// Round 15
// baseline (95349.518 us; speedup 1.0000x reference)
//
#include <hip/hip_runtime.h>
#include <hip/hip_bf16.h>
#include <cstddef>

// ---------------- problem constants ----------------
#define BB    32
#define T1    129
#define TT    128
#define SS    256
#define EE    512
#define HH    1024
#define KK    128
#define VV    128
#define VOC   8000
#define VOCP  8064
#define KLOG  1152          // H + V
#define NBW   128           // worker blocks
#define NBA   32            // attention blocks
#define NB2   (NBW + NBA)

typedef __bf16 bf16x8 __attribute__((ext_vector_type(8)));
typedef float  f32x4  __attribute__((ext_vector_type(4)));
typedef unsigned int u32x4 __attribute__((ext_vector_type(4)));
typedef int    i32x2  __attribute__((ext_vector_type(2)));

#define MFMA(a,b,c) __builtin_amdgcn_mfma_f32_16x16x32_bf16((a),(b),(c),0,0,0)
#define VMCNT0 do { asm volatile("s_waitcnt vmcnt(0)" ::: "memory"); \
                    __builtin_amdgcn_sched_barrier(0); } while (0)
#define MT() (long long)__builtin_amdgcn_s_memrealtime()

// Producers write through to the MALL (sc0 sc1); consumers use NORMAL cached
// loads of step-indexed single-use addresses (L2 can't hold a stale copy).
__device__ __forceinline__ void cstore16(const void* p, u32x4 v) {
    asm volatile("global_store_dwordx4 %0, %1, off sc0 sc1" :: "v"(p), "v"(v) : "memory");
}
__device__ __forceinline__ void cstore4i(const int* p, int v) {
    asm volatile("global_store_dword %0, %1, off sc0 sc1" :: "v"(p), "v"(v) : "memory");
}

// Flag polls (flags are monotonic step counters).
__device__ __forceinline__ void poll32v(const int* flags, int target, int lane)
{
    const int* p = flags + (lane & 31);
    for (;;) {
        int f;
        asm volatile("global_load_dword %0, %1, off sc0 sc1\n\ts_waitcnt vmcnt(0)"
                     : "=v"(f) : "v"(p) : "memory");
        if (__all(f >= target)) break;
        __builtin_amdgcn_s_sleep(1);
    }
}
__device__ __forceinline__ void poll128v(const int* flags, int target, int lane)
{
    const int* p = flags + lane * 2;
    for (;;) {
        i32x2 f;
        asm volatile("global_load_dwordx2 %0, %1, off sc0 sc1\n\ts_waitcnt vmcnt(0)"
                     : "=v"(f) : "v"(p) : "memory");
        if (__all(f.x >= target && f.y >= target)) break;
        __builtin_amdgcn_s_sleep(1);
    }
}

union bf8u { __hip_bfloat16 h[8]; bf16x8 v; };

__device__ __forceinline__ bf16x8 cvt8(float4 a, float4 b) {
    bf8u u;
    u.h[0] = __float2bfloat16(a.x); u.h[1] = __float2bfloat16(a.y);
    u.h[2] = __float2bfloat16(a.z); u.h[3] = __float2bfloat16(a.w);
    u.h[4] = __float2bfloat16(b.x); u.h[5] = __float2bfloat16(b.y);
    u.h[6] = __float2bfloat16(b.z); u.h[7] = __float2bfloat16(b.w);
    return u.v;
}
__device__ __forceinline__ float fsig(float x) { return 1.f / (1.f + __expf(-x)); }

// ---------------- prologue kernels ----------------
__global__ void pack_wout(const float* __restrict__ W, __hip_bfloat16* __restrict__ Wp)
{
    int v = blockIdx.y;
    int k = blockIdx.x * 256 + threadIdx.x;
    if (k >= KLOG) return;
    float w = (v < VOC) ? W[(size_t)v * KLOG + k] : 0.f;
    Wp[(size_t)v * KLOG + k] = __float2bfloat16(w);
}

__global__ void init_state(const float* __restrict__ enc,
                           __hip_bfloat16* __restrict__ H1s,
                           __hip_bfloat16* __restrict__ H2s,
                           int* __restrict__ bar)
{
    int i = blockIdx.x * 256 + threadIdx.x;
    if (i < 1024) bar[i] = 0;                 // flag1[0:128] flag2[128:256] flagc[256:288]
    if (i >= BB * HH) return;
    __hip_bfloat16 eb = __float2bfloat16(enc[i]);
    H1s[i] = eb;   // slot 0 = h1(-1)
    H2s[i] = eb;   // slot 0 = h2(-1)
}

__global__ void gather_emb(const int* __restrict__ tok, const float* __restrict__ emb,
                           __hip_bfloat16* __restrict__ Aemb)
{
    int bid = blockIdx.x;          // t*32 + b
    int t = bid >> 5, b = bid & 31;
    int id = tok[b * T1 + t];
    const float* er = emb + (size_t)id * EE;
    __hip_bfloat16* dst = Aemb + (size_t)bid * EE;
    for (int k = threadIdx.x; k < EE; k += 256)
        dst[k] = __float2bfloat16(er[k]);
}

// ---------------- timing probes: spin for 16x dbg[I] ticks -----------------
// probe<0>=16*P(worker poll), <1>=16*W(worker work), <2>=16*S(worker store),
// <3>=16*A(attn phase). Divide rocprof dur by 16 to read the phase total.
template<int I>
__global__ void probe(const long long* __restrict__ dbg)
{
    long long n = dbg[I] * 16;
    if (n < 0 || n > 8000000LL) n = 8000000LL;
    long long s = MT();
    while (MT() - s < n) {}
}

// ---------------- persistent decoder ----------------
// 160 blocks x 512 threads. Blocks 0..127: LSTM workers (8 hidden units each).
// Blocks 128..159: dedicated attention for batch b = bid-128 (Wq in regs).
__global__ __launch_bounds__(512, 2) void decoder_persistent(
    const float* __restrict__ Wih1, const float* __restrict__ Whh1, const float* __restrict__ b1v,
    const float* __restrict__ Wih2, const float* __restrict__ Whh2, const float* __restrict__ b2v,
    const float* __restrict__ Wq,   const float* __restrict__ bq,
    const float* __restrict__ keys, const float* __restrict__ vals,
    const __hip_bfloat16* __restrict__ Aemb,
    __hip_bfloat16* H1s, __hip_bfloat16* H2s, __hip_bfloat16* CTXs,
    __hip_bfloat16* Alog, int* bar, long long* dbg)
{
    const int bid = blockIdx.x;
    const int tid = threadIdx.x;
    const int w   = tid >> 6;
    const int cg  = w >> 2;
    const int kq  = w & 3;
    const int l   = tid & 63;
    const int l15 = l & 15, l4 = l >> 4;

    int* flag1 = bar;          // 128, h1 ready
    int* flag2 = bar + 128;    // 128, h2 ready
    int* flagc = bar + 256;    // 32,  ctx ready

    __shared__ float G[2][4][32][17];
    __shared__ alignas(16) __hip_bfloat16 hstage[32][8];
    __shared__ alignas(16) __hip_bfloat16 cstage[128];
    __shared__ alignas(16) float hs[HH];
    __shared__ float qs[KK];
    __shared__ float esl[SS];
    __shared__ float red[512];
    __shared__ float wmx[4], wsm[4];

    extern __shared__ __hip_bfloat16 kvls[];                 // dynamic 128 KB
    __hip_bfloat16 (*kls)[SS] = (__hip_bfloat16(*)[SS])kvls;             // [KK][SS]
    __hip_bfloat16 (*vls)[VV] = (__hip_bfloat16(*)[VV])(kvls + KK * SS); // [SS][VV]

    const bool tb = (tid == 0);

    if (bid < NBW) {
        // ================= WORKER =================
        const int n0 = bid * 32 + cg * 16;
        const bool wb = (bid == 40);
        long long tmark = 0, accP = 0, accW = 0, accS = 0;

        bf16x8 w1e[4], w1c, w1h[8], w2a[8], w2b[8];
        {
            const int col  = n0 + l15;
            const int orow = (col & 3) * HH + (col >> 2);   // packed rp=4j+g -> g*H+j
            #pragma unroll
            for (int s = 0; s < 4; ++s) {
                int k0 = kq * 128 + s * 32 + l4 * 8;
                const float* p0 = Wih1 + (size_t)orow * (EE + VV) + k0;
                w1e[s] = cvt8(*(const float4*)p0, *(const float4*)(p0 + 4));
            }
            {
                int k0 = kq * 32 + l4 * 8;
                const float* p0 = Wih1 + (size_t)orow * (EE + VV) + EE + k0;
                w1c = cvt8(*(const float4*)p0, *(const float4*)(p0 + 4));
            }
            #pragma unroll
            for (int s = 0; s < 8; ++s) {
                int k0 = kq * 256 + s * 32 + l4 * 8;
                const float* p1 = Whh1 + (size_t)orow * HH + k0;
                const float* p2 = Wih2 + (size_t)orow * HH + k0;
                const float* p3 = Whh2 + (size_t)orow * HH + k0;
                w1h[s] = cvt8(*(const float4*)p1, *(const float4*)(p1 + 4));
                w2a[s] = cvt8(*(const float4*)p2, *(const float4*)(p2 + 4));
                w2b[s] = cvt8(*(const float4*)p3, *(const float4*)(p3 + 4));
            }
        }

        float c1r = 0.f, c2r = 0.f;
        float gb1[4], gb2[4];
        {
            int jl = tid & 7;
            int j  = bid * 8 + jl;
            #pragma unroll
            for (int g = 0; g < 4; ++g) { gb1[g] = b1v[g * HH + j]; gb2[g] = b2v[g * HH + j]; }
        }

        // prologue pre-acc (slot-0, never overwritten; normal loads)
        f32x4 acc1A = {0,0,0,0}, acc1B = {0,0,0,0}, acc2A = {0,0,0,0}, acc2B = {0,0,0,0};
        #pragma unroll
        for (int s = 0; s < 4; ++s) {
            int k0 = kq * 128 + s * 32 + l4 * 8;
            bf16x8 a0 = *(const bf16x8*)(Aemb + (size_t)l15 * EE + k0);
            bf16x8 a1 = *(const bf16x8*)(Aemb + (size_t)(16 + l15) * EE + k0);
            acc1A = MFMA(a0, w1e[s], acc1A);
            acc1B = MFMA(a1, w1e[s], acc1B);
        }
        #pragma unroll
        for (int s = 0; s < 8; ++s) {
            int k0 = kq * 256 + s * 32 + l4 * 8;
            bf16x8 a0 = *(const bf16x8*)(H1s + (size_t)l15 * HH + k0);
            bf16x8 a1 = *(const bf16x8*)(H1s + (size_t)(16 + l15) * HH + k0);
            acc1A = MFMA(a0, w1h[s], acc1A);
            acc1B = MFMA(a1, w1h[s], acc1B);
            bf16x8 b0 = *(const bf16x8*)(H2s + (size_t)l15 * HH + k0);
            bf16x8 b1 = *(const bf16x8*)(H2s + (size_t)(16 + l15) * HH + k0);
            acc2A = MFMA(b0, w2b[s], acc2A);
            acc2B = MFMA(b1, w2b[s], acc2B);
        }

        bf16x8 fA[8], fB[8];
        if (wb && tb) tmark = MT();

        #pragma unroll 1
        for (int t = 0; t < TT; ++t) {
            const int rnd = t + 1;
            __hip_bfloat16* AlogT = Alog + (size_t)t * BB * KLOG;
            const __hip_bfloat16* H1t = H1s + (size_t)rnd * BB * HH;
            const __hip_bfloat16* H2t = H2s + (size_t)rnd * BB * HH;

            // ---- S1 ----
            if (t > 0) poll32v(flagc, t, l);                   // all waves
            if (wb && tb) { long long n = MT(); accP += n - tmark; tmark = n; }
            if (t > 0) {
                const __hip_bfloat16* Ct = CTXs + (size_t)t * BB * VV;
                int k0 = kq * 32 + l4 * 8;
                bf16x8 a0 = *(const bf16x8*)(Ct + (size_t)l15 * VV + k0);
                bf16x8 a1 = *(const bf16x8*)(Ct + (size_t)(16 + l15) * VV + k0);
                acc1A = MFMA(a0, w1c, acc1A);
                acc1B = MFMA(a1, w1c, acc1B);
            }
            #pragma unroll
            for (int r = 0; r < 4; ++r) {
                G[cg][kq][l4 * 4 + r][l15]      = acc1A[r];
                G[cg][kq][16 + l4 * 4 + r][l15] = acc1B[r];
            }
            acc1A = (f32x4){0,0,0,0}; acc1B = (f32x4){0,0,0,0};
            __syncthreads();
            if (tid < 256) {
                int b = tid >> 3, jl = tid & 7;
                int cg2 = jl >> 2, cb = (jl & 3) * 4;
                float g0 = G[cg2][0][b][cb+0] + G[cg2][1][b][cb+0] + G[cg2][2][b][cb+0] + G[cg2][3][b][cb+0] + gb1[0];
                float g1 = G[cg2][0][b][cb+1] + G[cg2][1][b][cb+1] + G[cg2][2][b][cb+1] + G[cg2][3][b][cb+1] + gb1[1];
                float g2 = G[cg2][0][b][cb+2] + G[cg2][1][b][cb+2] + G[cg2][2][b][cb+2] + G[cg2][3][b][cb+2] + gb1[2];
                float g3 = G[cg2][0][b][cb+3] + G[cg2][1][b][cb+3] + G[cg2][2][b][cb+3] + G[cg2][3][b][cb+3] + gb1[3];
                c1r = fsig(g1) * c1r + fsig(g0) * tanhf(g2);
                float h = fsig(g3) * tanhf(c1r);
                hstage[b][jl] = __float2bfloat16(h);
            }
            __syncthreads();
            if (wb && tb) { long long n = MT(); accW += n - tmark; tmark = n; }
            if (w == 0) {
                if (l < 32)
                    cstore16((void*)(H1t + (size_t)l * HH + bid * 8), *(const u32x4*)&hstage[l][0]);
                VMCNT0;
                if (l == 0) cstore4i(&flag1[bid], rnd);
            }
            if (wb && tb) { long long n = MT(); accS += n - tmark; tmark = n; }
            poll32v(flag1 + kq * 32, rnd, l);                  // my k-slice producers
            if (wb && tb) { long long n = MT(); accP += n - tmark; tmark = n; }

            // ---- S2 ----
            #pragma unroll
            for (int s = 0; s < 8; ++s) {
                int k0 = kq * 256 + s * 32 + l4 * 8;
                fA[s] = *(const bf16x8*)(H1t + (size_t)l15 * HH + k0);
                fB[s] = *(const bf16x8*)(H1t + (size_t)(16 + l15) * HH + k0);
            }
            #pragma unroll
            for (int s = 0; s < 8; ++s) {
                acc2A = MFMA(fA[s], w2a[s], acc2A);
                acc2B = MFMA(fB[s], w2a[s], acc2B);
                acc1A = MFMA(fA[s], w1h[s], acc1A);
                acc1B = MFMA(fB[s], w1h[s], acc1B);
            }
            #pragma unroll
            for (int r = 0; r < 4; ++r) {
                G[cg][kq][l4 * 4 + r][l15]      = acc2A[r];
                G[cg][kq][16 + l4 * 4 + r][l15] = acc2B[r];
            }
            acc2A = (f32x4){0,0,0,0}; acc2B = (f32x4){0,0,0,0};
            __syncthreads();
            if (tid < 256) {
                int b = tid >> 3, jl = tid & 7;
                int cg2 = jl >> 2, cb = (jl & 3) * 4;
                float g0 = G[cg2][0][b][cb+0] + G[cg2][1][b][cb+0] + G[cg2][2][b][cb+0] + G[cg2][3][b][cb+0] + gb2[0];
                float g1 = G[cg2][0][b][cb+1] + G[cg2][1][b][cb+1] + G[cg2][2][b][cb+1] + G[cg2][3][b][cb+1] + gb2[1];
                float g2 = G[cg2][0][b][cb+2] + G[cg2][1][b][cb+2] + G[cg2][2][b][cb+2] + G[cg2][3][b][cb+2] + gb2[2];
                float g3 = G[cg2][0][b][cb+3] + G[cg2][1][b][cb+3] + G[cg2][2][b][cb+3] + G[cg2][3][b][cb+3] + gb2[3];
                c2r = fsig(g1) * c2r + fsig(g0) * tanhf(g2);
                float h = fsig(g3) * tanhf(c2r);
                hstage[tid >> 3][tid & 7] = __float2bfloat16(h);
            }
            __syncthreads();
            if (wb && tb) { long long n = MT(); accW += n - tmark; tmark = n; }
            if (w == 0) {
                if (l < 32) {
                    u32x4 v = *(const u32x4*)&hstage[l][0];
                    cstore16((void*)(H2t + (size_t)l * HH + bid * 8), v);
                    *(u32x4*)(AlogT + (size_t)l * KLOG + bid * 8) = v;   // normal store
                }
                VMCNT0;
                if (l == 0) cstore4i(&flag2[bid], rnd);
            }
            if (wb && tb) { long long n = MT(); accS += n - tmark; tmark = n; }
            poll32v(flag2 + kq * 32, rnd, l);
            if (wb && tb) { long long n = MT(); accP += n - tmark; tmark = n; }

            // ---- S3: pre-acc gates2(t+1) += Whh2*h2(t); + emb(t+1) ----
            #pragma unroll
            for (int s = 0; s < 8; ++s) {
                int k0 = kq * 256 + s * 32 + l4 * 8;
                fA[s] = *(const bf16x8*)(H2t + (size_t)l15 * HH + k0);
                fB[s] = *(const bf16x8*)(H2t + (size_t)(16 + l15) * HH + k0);
            }
            #pragma unroll
            for (int s = 0; s < 8; ++s) {
                acc2A = MFMA(fA[s], w2b[s], acc2A);
                acc2B = MFMA(fB[s], w2b[s], acc2B);
            }
            if (t + 1 < TT) {
                const __hip_bfloat16* An = Aemb + (size_t)(t + 1) * BB * EE;
                #pragma unroll
                for (int s = 0; s < 4; ++s) {
                    int k0 = kq * 128 + s * 32 + l4 * 8;
                    bf16x8 a0 = *(const bf16x8*)(An + (size_t)l15 * EE + k0);
                    bf16x8 a1 = *(const bf16x8*)(An + (size_t)(16 + l15) * EE + k0);
                    acc1A = MFMA(a0, w1e[s], acc1A);
                    acc1B = MFMA(a1, w1e[s], acc1B);
                }
            }
            if (wb && tb) { long long n = MT(); accW += n - tmark; tmark = n; }
        }
        if (wb && tb) { dbg[0] = accP; dbg[1] = accW; dbg[2] = accS; }

    } else {
        // ================= ATTENTION (b = bid - 128) =================
        const int b  = bid - NBW;                 // 0..31  (r14 bug: was bid-32)
        const bool ab = (bid == NBW);
        long long tA = 0, accA = 0;

        // keys/vals -> LDS (bf16), once
        for (int i = tid; i < SS * KK; i += 512) {
            int s = i >> 7, k = i & 127;
            kls[k][s] = __float2bfloat16(keys[((size_t)b * SS + s) * KK + k]);
            vls[s][k] = __float2bfloat16(vals[((size_t)b * SS + s) * VV + k]);
        }
        // Wq -> registers: thread (kp=tid>>2, qc=tid&3) holds Wq[kp][qc*256..+256)
        const int kp = tid >> 2, qc = tid & 3;
        bf16x8 wq[32];
        {
            const float* src = Wq + (size_t)kp * HH + qc * 256;
            #pragma unroll
            for (int c = 0; c < 32; ++c)
                wq[c] = cvt8(*(const float4*)(src + c * 8), *(const float4*)(src + c * 8 + 4));
        }
        float bqr = bq[kp];
        __syncthreads();

        #pragma unroll 1
        for (int t = 0; t < TT; ++t) {
            const int rnd = t + 1;
            __hip_bfloat16* AlogT = Alog + (size_t)t * BB * KLOG;
            const __hip_bfloat16* H2t = H2s + (size_t)rnd * BB * HH;

            if (w == 0) poll128v(flag2, rnd, l);
            __syncthreads();
            if (ab && tb) tA = MT();

            bf16x8 hrow;
            if (tid < 128)
                hrow = *(const bf16x8*)(H2t + (size_t)b * HH + tid * 8);
            if (tid < 128) {
                #pragma unroll
                for (int e = 0; e < 8; ++e) hs[tid * 8 + e] = (float)hrow[e];
            }
            __syncthreads();
            {   // q[kp] from register Wq
                const float* hh = hs + qc * 256;
                float acc = 0.f;
                #pragma unroll
                for (int c = 0; c < 32; ++c) {
                    bf16x8 wv = wq[c];
                    #pragma unroll
                    for (int e = 0; e < 8; ++e) acc += (float)wv[e] * hh[c * 8 + e];
                }
                acc += __shfl_xor(acc, 1);
                acc += __shfl_xor(acc, 2);
                if (qc == 0) qs[kp] = acc + bqr;
            }
            __syncthreads();
            float en = 0.f;
            if (tid < SS) {
                #pragma unroll 8
                for (int k = 0; k < KK; ++k)
                    en += __bfloat162float(kls[k][tid]) * qs[k];
            }
            if (w < 4) {
                float m = en;
                #pragma unroll
                for (int off = 32; off > 0; off >>= 1)
                    m = fmaxf(m, __shfl_xor(m, off));
                if (l == 0) wmx[w] = m;
            }
            __syncthreads();
            float mx = fmaxf(fmaxf(wmx[0], wmx[1]), fmaxf(wmx[2], wmx[3]));
            if (w < 4) {
                float p = __expf(en - mx);
                esl[tid] = p;
                float sm = p;
                #pragma unroll
                for (int off = 32; off > 0; off >>= 1)
                    sm += __shfl_xor(sm, off);
                if (l == 0) wsm[w] = sm;
            }
            __syncthreads();
            float inv = 1.f / (wsm[0] + wsm[1] + wsm[2] + wsm[3]);
            {   // PV from LDS vals (bf16)
                int v = tid & 127, sh = tid >> 7;
                float acc = 0.f;
                #pragma unroll 4
                for (int i = 0; i < 64; ++i)
                    acc += esl[sh * 64 + i] * __bfloat162float(vls[sh * 64 + i][v]);
                red[tid] = acc;
            }
            __syncthreads();
            if (tid < VV) {
                float cv = (red[tid] + red[tid+128] + red[tid+256] + red[tid+384]) * inv;
                cstage[tid] = __float2bfloat16(cv);
            }
            __syncthreads();
            if (w == 0) {
                if (l < 16) {
                    u32x4 v = *(const u32x4*)&cstage[l * 8];
                    cstore16((void*)(CTXs + (size_t)rnd * BB * VV + (size_t)b * VV + l * 8), v);
                    *(u32x4*)(AlogT + (size_t)b * KLOG + HH + l * 8) = v;  // normal store
                }
                VMCNT0;
                if (l == 0) cstore4i(&flagc[b], rnd);
            }
            if (ab && tb) accA += MT() - tA;
        }
        if (ab && tb) dbg[3] = accA;
    }
}

// ---------------- deferred logits GEMM ----------------
__global__ __launch_bounds__(256) void logits_gemm(
    const __hip_bfloat16* __restrict__ Alog,
    const __hip_bfloat16* __restrict__ W,
    const float* __restrict__ bout,
    float* __restrict__ out)
{
    int n0 = blockIdx.x * 128;
    int m0 = blockIdx.y * 128;
    int wv = threadIdx.x >> 6, l = threadIdx.x & 63;
    int l15 = l & 15, l4 = l >> 4;

    f32x4 acc[8][2] = {};
    const __hip_bfloat16* Ap = Alog + (size_t)(m0 + l15) * KLOG + l4 * 8;
    const __hip_bfloat16* Bp = W    + (size_t)(n0 + wv * 32 + l15) * KLOG + l4 * 8;

    for (int kt = 0; kt < KLOG; kt += 32) {
        bf16x8 b0 = *(const bf16x8*)(Bp + kt);
        bf16x8 b1 = *(const bf16x8*)(Bp + (size_t)16 * KLOG + kt);
        #pragma unroll
        for (int ms = 0; ms < 8; ++ms) {
            bf16x8 a = *(const bf16x8*)(Ap + (size_t)ms * 16 * KLOG + kt);
            acc[ms][0] = MFMA(a, b0, acc[ms][0]);
            acc[ms][1] = MFMA(a, b1, acc[ms][1]);
        }
    }
    #pragma unroll
    for (int ms = 0; ms < 8; ++ms)
        #pragma unroll
        for (int ns = 0; ns < 2; ++ns) {
            int col = n0 + wv * 32 + ns * 16 + l15;
            if (col < VOC) {
                float bias = bout[col];
                #pragma unroll
                for (int r = 0; r < 4; ++r) {
                    int m = m0 + ms * 16 + l4 * 4 + r;
                    int b = m & 31, t = m >> 5;
                    out[((size_t)b * TT + t) * VOC + col] = acc[ms][ns][r] + bias;
                }
            }
        }
}

// ---------------- host ----------------
extern "C" void kernel_launch(void* const* d_in, const int* in_sizes, int n_in,
                              void* d_out, int out_size, void* d_ws, size_t ws_size,
                              hipStream_t stream)
{
    (void)in_sizes; (void)n_in; (void)out_size; (void)ws_size;
    const int*   dec  = (const int*)  d_in[0];
    const float* enc  = (const float*)d_in[2];
    const float* keys = (const float*)d_in[3];
    const float* vals = (const float*)d_in[4];
    const float* emb  = (const float*)d_in[5];
    const float* Wih1 = (const float*)d_in[6];
    const float* Whh1 = (const float*)d_in[7];
    const float* b1   = (const float*)d_in[8];
    const float* Wih2 = (const float*)d_in[9];
    const float* Whh2 = (const float*)d_in[10];
    const float* b2   = (const float*)d_in[11];
    const float* Wq   = (const float*)d_in[12];
    const float* bq   = (const float*)d_in[13];
    const float* Wout = (const float*)d_in[14];
    const float* bout = (const float*)d_in[15];
    float* out = (float*)d_out;

    // workspace carve (~50 MB)
    char* p = (char*)d_ws;
    __hip_bfloat16* WoutP = (__hip_bfloat16*)p; p += (size_t)VOCP * KLOG * 2;          // 18.6 MB
    __hip_bfloat16* Alog  = (__hip_bfloat16*)p; p += (size_t)TT * BB * KLOG * 2;       // 9.4 MB
    __hip_bfloat16* Aemb  = (__hip_bfloat16*)p; p += (size_t)TT * BB * EE * 2;         // 4.2 MB
    __hip_bfloat16* H1s   = (__hip_bfloat16*)p; p += (size_t)(TT + 1) * BB * HH * 2;   // 8.45 MB
    __hip_bfloat16* H2s   = (__hip_bfloat16*)p; p += (size_t)(TT + 1) * BB * HH * 2;   // 8.45 MB
    __hip_bfloat16* CTXs  = (__hip_bfloat16*)p; p += (size_t)(TT + 1) * BB * VV * 2;   // 1.06 MB
    int* bar = (int*)p; p += 4096;
    long long* dbg = (long long*)p; p += 256;

    pack_wout  <<<dim3((KLOG + 255) / 256, VOCP), 256, 0, stream>>>(Wout, WoutP);
    init_state <<<dim3(128), 256, 0, stream>>>(enc, H1s, H2s, bar);
    gather_emb <<<dim3(TT * BB), 256, 0, stream>>>(dec, emb, Aemb);

    decoder_persistent<<<dim3(NB2), 512, KK * SS * 2 + SS * VV * 2, stream>>>(
        Wih1, Whh1, b1, Wih2, Whh2, b2, Wq, bq, keys, vals,
        Aemb, H1s, H2s, CTXs, Alog, bar, dbg);

    logits_gemm<<<dim3(VOCP / 128, (BB * TT) / 128), 256, 0, stream>>>(Alog, WoutP, bout, out);

    // probes: dur/16 = phase totals. Order: P, W, S, A.
    probe<0><<<dim3(1), 1, 0, stream>>>(dbg);
    probe<1><<<dim3(1), 1, 0, stream>>>(dbg);
    probe<2><<<dim3(1), 1, 0, stream>>>(dbg);
    probe<3><<<dim3(1), 1, 0, stream>>>(dbg);
}

// Round 16
// 29650.055 us; speedup vs baseline: 3.2158x; 3.2158x over previous
//
#include <hip/hip_runtime.h>
#include <hip/hip_bf16.h>
#include <cstddef>

// ---------------- problem constants ----------------
#define BB    32
#define T1    129
#define TT    128
#define SS    256
#define EE    512
#define HH    1024
#define KK    128
#define VV    128
#define VOC   8000
#define VOCP  8064
#define KLOG  1152          // H + V
#define NBW   128           // worker blocks
#define NBAT  128           // attention sub-blocks (4 per batch, 64 s each)
#define NB2   (NBW + NBAT)  // 256 total (all resident: <=2 blocks/CU @ 57KB LDS)

typedef __bf16 bf16x8 __attribute__((ext_vector_type(8)));
typedef float  f32x4  __attribute__((ext_vector_type(4)));
typedef unsigned int u32x4 __attribute__((ext_vector_type(4)));
typedef int    i32x2  __attribute__((ext_vector_type(2)));

#define MFMA(a,b,c) __builtin_amdgcn_mfma_f32_16x16x32_bf16((a),(b),(c),0,0,0)
#define VMCNT0 do { asm volatile("s_waitcnt vmcnt(0)" ::: "memory"); \
                    __builtin_amdgcn_sched_barrier(0); } while (0)
#define MT() (long long)__builtin_amdgcn_s_memrealtime()

// Write-through (MALL) stores; consumers use normal loads of step-indexed
// single-use addresses (reader L2 can't hold stale copies).
__device__ __forceinline__ void cstore16(const void* p, u32x4 v) {
    asm volatile("global_store_dwordx4 %0, %1, off sc0 sc1" :: "v"(p), "v"(v) : "memory");
}
__device__ __forceinline__ void cstore4i(const int* p, int v) {
    asm volatile("global_store_dword %0, %1, off sc0 sc1" :: "v"(p), "v"(v) : "memory");
}
__device__ __forceinline__ void cstore4f(const float* p, float v) {
    asm volatile("global_store_dword %0, %1, off sc0 sc1" :: "v"(p), "v"(v) : "memory");
}

// Flag polls (flags are monotonic step counters).
__device__ __forceinline__ void poll32v(const int* flags, int target, int lane)
{
    const int* p = flags + (lane & 31);
    for (;;) {
        int f;
        asm volatile("global_load_dword %0, %1, off sc0 sc1\n\ts_waitcnt vmcnt(0)"
                     : "=v"(f) : "v"(p) : "memory");
        if (__all(f >= target)) break;
        __builtin_amdgcn_s_sleep(1);
    }
}
__device__ __forceinline__ void poll128v(const int* flags, int target, int lane)
{
    const int* p = flags + lane * 2;
    for (;;) {
        i32x2 f;
        asm volatile("global_load_dwordx2 %0, %1, off sc0 sc1\n\ts_waitcnt vmcnt(0)"
                     : "=v"(f) : "v"(p) : "memory");
        if (__all(f.x >= target && f.y >= target)) break;
        __builtin_amdgcn_s_sleep(1);
    }
}
__device__ __forceinline__ void poll3v(const int* flags, int target, int lane)
{
    const int* p = flags + ((lane < 3) ? lane : 0);
    for (;;) {
        int f;
        asm volatile("global_load_dword %0, %1, off sc0 sc1\n\ts_waitcnt vmcnt(0)"
                     : "=v"(f) : "v"(p) : "memory");
        if (__all(f >= target)) break;
        __builtin_amdgcn_s_sleep(1);
    }
}

union bf8u { __hip_bfloat16 h[8]; bf16x8 v; };

__device__ __forceinline__ bf16x8 cvt8(float4 a, float4 b) {
    bf8u u;
    u.h[0] = __float2bfloat16(a.x); u.h[1] = __float2bfloat16(a.y);
    u.h[2] = __float2bfloat16(a.z); u.h[3] = __float2bfloat16(a.w);
    u.h[4] = __float2bfloat16(b.x); u.h[5] = __float2bfloat16(b.y);
    u.h[6] = __float2bfloat16(b.z); u.h[7] = __float2bfloat16(b.w);
    return u.v;
}
__device__ __forceinline__ float fsig(float x) { return 1.f / (1.f + __expf(-x)); }

// ---------------- prologue kernels ----------------
__global__ void pack_wout(const float* __restrict__ W, __hip_bfloat16* __restrict__ Wp)
{
    int v = blockIdx.y;
    int k = blockIdx.x * 256 + threadIdx.x;
    if (k >= KLOG) return;
    float w = (v < VOC) ? W[(size_t)v * KLOG + k] : 0.f;
    Wp[(size_t)v * KLOG + k] = __float2bfloat16(w);
}

__global__ void init_state(const float* __restrict__ enc,
                           __hip_bfloat16* __restrict__ H1s,
                           __hip_bfloat16* __restrict__ H2s,
                           int* __restrict__ bar)
{
    int i = blockIdx.x * 256 + threadIdx.x;
    if (i < 1024) bar[i] = 0;   // flag1[0:128] flag2[128:256] flagc[256:288] flagp[288:416]
    if (i >= BB * HH) return;
    __hip_bfloat16 eb = __float2bfloat16(enc[i]);
    H1s[i] = eb;   // slot 0 = h1(-1)
    H2s[i] = eb;   // slot 0 = h2(-1)
}

__global__ void gather_emb(const int* __restrict__ tok, const float* __restrict__ emb,
                           __hip_bfloat16* __restrict__ Aemb)
{
    int bid = blockIdx.x;          // t*32 + b
    int t = bid >> 5, b = bid & 31;
    int id = tok[b * T1 + t];
    const float* er = emb + (size_t)id * EE;
    __hip_bfloat16* dst = Aemb + (size_t)bid * EE;
    for (int k = threadIdx.x; k < EE; k += 256)
        dst[k] = __float2bfloat16(er[k]);
}

// ---------------- timing probes ----------------
// probe<I> identity = Workgroup_Size ((I+1)*64). Duration = 4*dbg[I] + 1ms.
// dbg: [0]=P worker-poll, [1]=W worker-work, [2]=S worker-store, [3]=A attn.
template<int I>
__global__ void probe(const long long* __restrict__ dbg)
{
    long long n = dbg[I] * 4 + 100000LL;
    if (n < 0 || n > 10000000LL) n = 10000000LL;
    long long s = MT();
    while (MT() - s < n) {}
}

// ---------------- persistent decoder ----------------
// 256 blocks x 512 threads. Blocks 0..127: LSTM workers (8 hidden units each).
// Blocks 128..255: attention sub-blocks; a=bid-128, batch b=a>>2, s-quarter
// iq=a&3 owning s in [iq*64, iq*64+64). iq==0 is the combiner for batch b.
__global__ __launch_bounds__(512, 2) void decoder_persistent(
    const float* __restrict__ Wih1, const float* __restrict__ Whh1, const float* __restrict__ b1v,
    const float* __restrict__ Wih2, const float* __restrict__ Whh2, const float* __restrict__ b2v,
    const float* __restrict__ Wq,   const float* __restrict__ bq,
    const float* __restrict__ keys, const float* __restrict__ vals,
    const __hip_bfloat16* __restrict__ Aemb,
    __hip_bfloat16* H1s, __hip_bfloat16* H2s, __hip_bfloat16* CTXs,
    float* PARTs, __hip_bfloat16* Alog, int* bar, long long* dbg)
{
    const int bid = blockIdx.x;
    const int tid = threadIdx.x;
    const int w   = tid >> 6;
    const int cg  = w >> 2;
    const int kq  = w & 3;
    const int l   = tid & 63;
    const int l15 = l & 15, l4 = l >> 4;

    int* flag1 = bar;          // 128, h1 ready
    int* flag2 = bar + 128;    // 128, h2 ready
    int* flagc = bar + 256;    // 32,  ctx ready
    int* flagp = bar + 288;    // 128, attn partial ready

    __shared__ float G[2][4][32][17];
    __shared__ alignas(16) __hip_bfloat16 hstage[32][8];
    __shared__ alignas(16) __hip_bfloat16 cstage[128];
    __shared__ alignas(16) float hs[HH];
    __shared__ float qs[KK];
    __shared__ float esl[64];
    __shared__ alignas(16) float pvl[128];
    __shared__ float red[512];
    __shared__ float wmx[4], wsm[4];

    extern __shared__ __hip_bfloat16 kvls[];                 // dynamic 32 KB
    __hip_bfloat16 (*kls)[64] = (__hip_bfloat16(*)[64])kvls;             // [KK][64]
    __hip_bfloat16 (*vls)[VV] = (__hip_bfloat16(*)[VV])(kvls + KK * 64); // [64][VV]

    const bool tb = (tid == 0);

    if (bid < NBW) {
        // ================= WORKER =================
        const int n0 = bid * 32 + cg * 16;
        const bool wb = (bid == 40);
        long long tmark = 0, accP = 0, accW = 0, accS = 0;

        bf16x8 w1e[4], w1c, w1h[8], w2a[8], w2b[8];
        {
            const int col  = n0 + l15;
            const int orow = (col & 3) * HH + (col >> 2);   // packed rp=4j+g -> g*H+j
            #pragma unroll
            for (int s = 0; s < 4; ++s) {
                int k0 = kq * 128 + s * 32 + l4 * 8;
                const float* p0 = Wih1 + (size_t)orow * (EE + VV) + k0;
                w1e[s] = cvt8(*(const float4*)p0, *(const float4*)(p0 + 4));
            }
            {
                int k0 = kq * 32 + l4 * 8;
                const float* p0 = Wih1 + (size_t)orow * (EE + VV) + EE + k0;
                w1c = cvt8(*(const float4*)p0, *(const float4*)(p0 + 4));
            }
            #pragma unroll
            for (int s = 0; s < 8; ++s) {
                int k0 = kq * 256 + s * 32 + l4 * 8;
                const float* p1 = Whh1 + (size_t)orow * HH + k0;
                const float* p2 = Wih2 + (size_t)orow * HH + k0;
                const float* p3 = Whh2 + (size_t)orow * HH + k0;
                w1h[s] = cvt8(*(const float4*)p1, *(const float4*)(p1 + 4));
                w2a[s] = cvt8(*(const float4*)p2, *(const float4*)(p2 + 4));
                w2b[s] = cvt8(*(const float4*)p3, *(const float4*)(p3 + 4));
            }
        }

        float c1r = 0.f, c2r = 0.f;
        float gb1[4], gb2[4];
        {
            int jl = tid & 7;
            int j  = bid * 8 + jl;
            #pragma unroll
            for (int g = 0; g < 4; ++g) { gb1[g] = b1v[g * HH + j]; gb2[g] = b2v[g * HH + j]; }
        }

        // prologue pre-acc (slot-0, never overwritten; normal loads)
        f32x4 acc1A = {0,0,0,0}, acc1B = {0,0,0,0}, acc2A = {0,0,0,0}, acc2B = {0,0,0,0};
        #pragma unroll
        for (int s = 0; s < 4; ++s) {
            int k0 = kq * 128 + s * 32 + l4 * 8;
            bf16x8 a0 = *(const bf16x8*)(Aemb + (size_t)l15 * EE + k0);
            bf16x8 a1 = *(const bf16x8*)(Aemb + (size_t)(16 + l15) * EE + k0);
            acc1A = MFMA(a0, w1e[s], acc1A);
            acc1B = MFMA(a1, w1e[s], acc1B);
        }
        #pragma unroll
        for (int s = 0; s < 8; ++s) {
            int k0 = kq * 256 + s * 32 + l4 * 8;
            bf16x8 a0 = *(const bf16x8*)(H1s + (size_t)l15 * HH + k0);
            bf16x8 a1 = *(const bf16x8*)(H1s + (size_t)(16 + l15) * HH + k0);
            acc1A = MFMA(a0, w1h[s], acc1A);
            acc1B = MFMA(a1, w1h[s], acc1B);
            bf16x8 b0 = *(const bf16x8*)(H2s + (size_t)l15 * HH + k0);
            bf16x8 b1 = *(const bf16x8*)(H2s + (size_t)(16 + l15) * HH + k0);
            acc2A = MFMA(b0, w2b[s], acc2A);
            acc2B = MFMA(b1, w2b[s], acc2B);
        }

        bf16x8 fA[8], fB[8];
        if (wb && tb) tmark = MT();

        #pragma unroll 1
        for (int t = 0; t < TT; ++t) {
            const int rnd = t + 1;
            __hip_bfloat16* AlogT = Alog + (size_t)t * BB * KLOG;
            const __hip_bfloat16* H1t = H1s + (size_t)rnd * BB * HH;
            const __hip_bfloat16* H2t = H2s + (size_t)rnd * BB * HH;

            // ---- S1 ----
            if (t > 0) poll32v(flagc, t, l);
            if (wb && tb) { long long n = MT(); accP += n - tmark; tmark = n; }
            if (t > 0) {
                const __hip_bfloat16* Ct = CTXs + (size_t)t * BB * VV;
                int k0 = kq * 32 + l4 * 8;
                bf16x8 a0 = *(const bf16x8*)(Ct + (size_t)l15 * VV + k0);
                bf16x8 a1 = *(const bf16x8*)(Ct + (size_t)(16 + l15) * VV + k0);
                acc1A = MFMA(a0, w1c, acc1A);
                acc1B = MFMA(a1, w1c, acc1B);
            }
            #pragma unroll
            for (int r = 0; r < 4; ++r) {
                G[cg][kq][l4 * 4 + r][l15]      = acc1A[r];
                G[cg][kq][16 + l4 * 4 + r][l15] = acc1B[r];
            }
            acc1A = (f32x4){0,0,0,0}; acc1B = (f32x4){0,0,0,0};
            __syncthreads();
            if (tid < 256) {
                int b = tid >> 3, jl = tid & 7;
                int cg2 = jl >> 2, cb = (jl & 3) * 4;
                float g0 = G[cg2][0][b][cb+0] + G[cg2][1][b][cb+0] + G[cg2][2][b][cb+0] + G[cg2][3][b][cb+0] + gb1[0];
                float g1 = G[cg2][0][b][cb+1] + G[cg2][1][b][cb+1] + G[cg2][2][b][cb+1] + G[cg2][3][b][cb+1] + gb1[1];
                float g2 = G[cg2][0][b][cb+2] + G[cg2][1][b][cb+2] + G[cg2][2][b][cb+2] + G[cg2][3][b][cb+2] + gb1[2];
                float g3 = G[cg2][0][b][cb+3] + G[cg2][1][b][cb+3] + G[cg2][2][b][cb+3] + G[cg2][3][b][cb+3] + gb1[3];
                c1r = fsig(g1) * c1r + fsig(g0) * tanhf(g2);
                float h = fsig(g3) * tanhf(c1r);
                hstage[b][jl] = __float2bfloat16(h);
            }
            __syncthreads();
            if (wb && tb) { long long n = MT(); accW += n - tmark; tmark = n; }
            if (w == 0) {
                if (l < 32)
                    cstore16((void*)(H1t + (size_t)l * HH + bid * 8), *(const u32x4*)&hstage[l][0]);
                VMCNT0;
                if (l == 0) cstore4i(&flag1[bid], rnd);
            }
            if (wb && tb) { long long n = MT(); accS += n - tmark; tmark = n; }
            poll32v(flag1 + kq * 32, rnd, l);                  // my k-slice producers
            if (wb && tb) { long long n = MT(); accP += n - tmark; tmark = n; }

            // ---- S2 ----
            #pragma unroll
            for (int s = 0; s < 8; ++s) {
                int k0 = kq * 256 + s * 32 + l4 * 8;
                fA[s] = *(const bf16x8*)(H1t + (size_t)l15 * HH + k0);
                fB[s] = *(const bf16x8*)(H1t + (size_t)(16 + l15) * HH + k0);
            }
            #pragma unroll
            for (int s = 0; s < 8; ++s) {
                acc2A = MFMA(fA[s], w2a[s], acc2A);
                acc2B = MFMA(fB[s], w2a[s], acc2B);
                acc1A = MFMA(fA[s], w1h[s], acc1A);
                acc1B = MFMA(fB[s], w1h[s], acc1B);
            }
            #pragma unroll
            for (int r = 0; r < 4; ++r) {
                G[cg][kq][l4 * 4 + r][l15]      = acc2A[r];
                G[cg][kq][16 + l4 * 4 + r][l15] = acc2B[r];
            }
            acc2A = (f32x4){0,0,0,0}; acc2B = (f32x4){0,0,0,0};
            __syncthreads();
            if (tid < 256) {
                int b = tid >> 3, jl = tid & 7;
                int cg2 = jl >> 2, cb = (jl & 3) * 4;
                float g0 = G[cg2][0][b][cb+0] + G[cg2][1][b][cb+0] + G[cg2][2][b][cb+0] + G[cg2][3][b][cb+0] + gb2[0];
                float g1 = G[cg2][0][b][cb+1] + G[cg2][1][b][cb+1] + G[cg2][2][b][cb+1] + G[cg2][3][b][cb+1] + gb2[1];
                float g2 = G[cg2][0][b][cb+2] + G[cg2][1][b][cb+2] + G[cg2][2][b][cb+2] + G[cg2][3][b][cb+2] + gb2[2];
                float g3 = G[cg2][0][b][cb+3] + G[cg2][1][b][cb+3] + G[cg2][2][b][cb+3] + G[cg2][3][b][cb+3] + gb2[3];
                c2r = fsig(g1) * c2r + fsig(g0) * tanhf(g2);
                float h = fsig(g3) * tanhf(c2r);
                hstage[tid >> 3][tid & 7] = __float2bfloat16(h);
            }
            __syncthreads();
            if (wb && tb) { long long n = MT(); accW += n - tmark; tmark = n; }
            if (w == 0) {
                if (l < 32) {
                    u32x4 v = *(const u32x4*)&hstage[l][0];
                    cstore16((void*)(H2t + (size_t)l * HH + bid * 8), v);
                    *(u32x4*)(AlogT + (size_t)l * KLOG + bid * 8) = v;   // normal store
                }
                VMCNT0;
                if (l == 0) cstore4i(&flag2[bid], rnd);
            }
            if (wb && tb) { long long n = MT(); accS += n - tmark; tmark = n; }
            poll32v(flag2 + kq * 32, rnd, l);
            if (wb && tb) { long long n = MT(); accP += n - tmark; tmark = n; }

            // ---- S3: pre-acc gates2(t+1) += Whh2*h2(t); + emb(t+1) ----
            #pragma unroll
            for (int s = 0; s < 8; ++s) {
                int k0 = kq * 256 + s * 32 + l4 * 8;
                fA[s] = *(const bf16x8*)(H2t + (size_t)l15 * HH + k0);
                fB[s] = *(const bf16x8*)(H2t + (size_t)(16 + l15) * HH + k0);
            }
            #pragma unroll
            for (int s = 0; s < 8; ++s) {
                acc2A = MFMA(fA[s], w2b[s], acc2A);
                acc2B = MFMA(fB[s], w2b[s], acc2B);
            }
            if (t + 1 < TT) {
                const __hip_bfloat16* An = Aemb + (size_t)(t + 1) * BB * EE;
                #pragma unroll
                for (int s = 0; s < 4; ++s) {
                    int k0 = kq * 128 + s * 32 + l4 * 8;
                    bf16x8 a0 = *(const bf16x8*)(An + (size_t)l15 * EE + k0);
                    bf16x8 a1 = *(const bf16x8*)(An + (size_t)(16 + l15) * EE + k0);
                    acc1A = MFMA(a0, w1e[s], acc1A);
                    acc1B = MFMA(a1, w1e[s], acc1B);
                }
            }
            if (wb && tb) { long long n = MT(); accW += n - tmark; tmark = n; }
        }
        if (wb && tb) { dbg[0] = accP; dbg[1] = accW; dbg[2] = accS; }

    } else {
        // ================= ATTENTION sub-block =================
        const int a  = bid - NBW;      // 0..127
        const int b  = a >> 2;         // batch
        const int iq = a & 3;          // s-quarter
        const int s0 = iq * 64;
        const bool comb = (iq == 0);   // combiner for batch b
        const bool ab = (bid == NBW);  // instrumented block (combiner, b=0)
        long long tA = 0, accA = 0;

        // K/V quarter -> LDS (bf16), once
        for (int i = tid; i < 64 * KK; i += 512) {
            int sl = i >> 7, k = i & 127;
            kls[k][sl] = __float2bfloat16(keys[((size_t)b * SS + s0 + sl) * KK + k]);
            vls[sl][k] = __float2bfloat16(vals[((size_t)b * SS + s0 + sl) * VV + k]);
        }
        // Wq -> registers: thread (kp=tid>>2, qc=tid&3) holds Wq[kp][qc*256..+256)
        const int kp = tid >> 2, qc = tid & 3;
        bf16x8 wq[32];
        {
            const float* src = Wq + (size_t)kp * HH + qc * 256;
            #pragma unroll
            for (int c = 0; c < 32; ++c)
                wq[c] = cvt8(*(const float4*)(src + c * 8), *(const float4*)(src + c * 8 + 4));
        }
        float bqr = bq[kp];
        __syncthreads();

        #pragma unroll 1
        for (int t = 0; t < TT; ++t) {
            const int rnd = t + 1;
            __hip_bfloat16* AlogT = Alog + (size_t)t * BB * KLOG;
            const __hip_bfloat16* H2t = H2s + (size_t)rnd * BB * HH;
            float* PARTt = PARTs + (size_t)rnd * NBAT * 132;

            if (w == 0) poll128v(flag2, rnd, l);
            __syncthreads();
            if (ab && tb) tA = MT();

            // h2[b] -> fp32 LDS
            bf16x8 hrow;
            if (tid < 128)
                hrow = *(const bf16x8*)(H2t + (size_t)b * HH + tid * 8);
            if (tid < 128) {
                #pragma unroll
                for (int e = 0; e < 8; ++e) hs[tid * 8 + e] = (float)hrow[e];
            }
            __syncthreads();
            {   // q[kp] from register Wq
                const float* hh = hs + qc * 256;
                float acc = 0.f;
                #pragma unroll
                for (int c = 0; c < 32; ++c) {
                    bf16x8 wv = wq[c];
                    #pragma unroll
                    for (int e = 0; e < 8; ++e) acc += (float)wv[e] * hh[c * 8 + e];
                }
                acc += __shfl_xor(acc, 1);
                acc += __shfl_xor(acc, 2);
                if (qc == 0) qs[kp] = acc + bqr;
            }
            __syncthreads();
            // energy for 64 s: 256 threads, sl=tid>>2, kc=tid&3 (32 k each)
            if (tid < 256) {
                int sl = tid >> 2, kc = tid & 3;
                float acc = 0.f;
                #pragma unroll 8
                for (int c = 0; c < 32; ++c) {
                    int k = kc * 32 + c;
                    acc += __bfloat162float(kls[k][sl]) * qs[k];
                }
                acc += __shfl_xor(acc, 1);
                acc += __shfl_xor(acc, 2);
                if (kc == 0) esl[sl] = acc;
            }
            __syncthreads();
            // local softmax over 64 (wave 0)
            if (w == 0) {
                float e2 = esl[l];
                float m = e2;
                #pragma unroll
                for (int off = 32; off > 0; off >>= 1)
                    m = fmaxf(m, __shfl_xor(m, off));
                float pp = __expf(e2 - m);
                esl[l] = pp;
                float sm = pp;
                #pragma unroll
                for (int off = 32; off > 0; off >>= 1)
                    sm += __shfl_xor(sm, off);
                if (l == 0) { wmx[0] = m; wsm[0] = sm; }
            }
            __syncthreads();
            // PV partial: v=tid&127, sh=tid>>7 handles 16 s
            {
                int v = tid & 127, sh = tid >> 7;
                float acc = 0.f;
                #pragma unroll 4
                for (int i2 = 0; i2 < 16; ++i2) {
                    int sl = sh * 16 + i2;
                    acc += esl[sl] * __bfloat162float(vls[sl][v]);
                }
                red[tid] = acc;
            }
            __syncthreads();
            if (tid < 128)
                pvl[tid] = red[tid] + red[tid + 128] + red[tid + 256] + red[tid + 384];
            __syncthreads();

            if (!comb) {
                // publish partial (pv[128], m, sum) write-through
                if (w == 0) {
                    float* dst = PARTt + (size_t)a * 132;
                    if (l < 32)
                        cstore16((void*)(dst + l * 4), *(const u32x4*)&pvl[l * 4]);
                    if (l == 32) { cstore4f(dst + 128, wmx[0]); cstore4f(dst + 129, wsm[0]); }
                    VMCNT0;
                    if (l == 0) cstore4i(&flagp[a], rnd);
                }
            } else {
                // combine 4 partials -> ctx
                if (w == 0) poll3v(flagp + a + 1, rnd, l);
                __syncthreads();
                if (tid < 128) {
                    const float* p1 = PARTt + (size_t)(a + 1) * 132;
                    const float* p2 = PARTt + (size_t)(a + 2) * 132;
                    const float* p3 = PARTt + (size_t)(a + 3) * 132;
                    float m0 = wmx[0], s0v = wsm[0];
                    float m1 = p1[128], s1 = p1[129];
                    float m2 = p2[128], s2 = p2[129];
                    float m3 = p3[128], s3 = p3[129];
                    float M = fmaxf(fmaxf(m0, m1), fmaxf(m2, m3));
                    float w0 = __expf(m0 - M), w1 = __expf(m1 - M);
                    float w2 = __expf(m2 - M), w3 = __expf(m3 - M);
                    float S = w0 * s0v + w1 * s1 + w2 * s2 + w3 * s3;
                    float cv = (w0 * pvl[tid] + w1 * p1[tid] + w2 * p2[tid] + w3 * p3[tid]) / S;
                    cstage[tid] = __float2bfloat16(cv);
                }
                __syncthreads();
                if (w == 0) {
                    if (l < 16) {
                        u32x4 v = *(const u32x4*)&cstage[l * 8];
                        cstore16((void*)(CTXs + (size_t)rnd * BB * VV + (size_t)b * VV + l * 8), v);
                        *(u32x4*)(AlogT + (size_t)b * KLOG + HH + l * 8) = v;  // normal store
                    }
                    VMCNT0;
                    if (l == 0) cstore4i(&flagc[b], rnd);
                }
            }
            if (ab && tb) accA += MT() - tA;
        }
        if (ab && tb) dbg[3] = accA;
    }
}

// ---------------- deferred logits GEMM ----------------
__global__ __launch_bounds__(256) void logits_gemm(
    const __hip_bfloat16* __restrict__ Alog,
    const __hip_bfloat16* __restrict__ W,
    const float* __restrict__ bout,
    float* __restrict__ out)
{
    int n0 = blockIdx.x * 128;
    int m0 = blockIdx.y * 128;
    int wv = threadIdx.x >> 6, l = threadIdx.x & 63;
    int l15 = l & 15, l4 = l >> 4;

    f32x4 acc[8][2] = {};
    const __hip_bfloat16* Ap = Alog + (size_t)(m0 + l15) * KLOG + l4 * 8;
    const __hip_bfloat16* Bp = W    + (size_t)(n0 + wv * 32 + l15) * KLOG + l4 * 8;

    for (int kt = 0; kt < KLOG; kt += 32) {
        bf16x8 b0 = *(const bf16x8*)(Bp + kt);
        bf16x8 b1 = *(const bf16x8*)(Bp + (size_t)16 * KLOG + kt);
        #pragma unroll
        for (int ms = 0; ms < 8; ++ms) {
            bf16x8 a = *(const bf16x8*)(Ap + (size_t)ms * 16 * KLOG + kt);
            acc[ms][0] = MFMA(a, b0, acc[ms][0]);
            acc[ms][1] = MFMA(a, b1, acc[ms][1]);
        }
    }
    #pragma unroll
    for (int ms = 0; ms < 8; ++ms)
        #pragma unroll
        for (int ns = 0; ns < 2; ++ns) {
            int col = n0 + wv * 32 + ns * 16 + l15;
            if (col < VOC) {
                float bias = bout[col];
                #pragma unroll
                for (int r = 0; r < 4; ++r) {
                    int m = m0 + ms * 16 + l4 * 4 + r;
                    int b = m & 31, t = m >> 5;
                    out[((size_t)b * TT + t) * VOC + col] = acc[ms][ns][r] + bias;
                }
            }
        }
}

// ---------------- host ----------------
extern "C" void kernel_launch(void* const* d_in, const int* in_sizes, int n_in,
                              void* d_out, int out_size, void* d_ws, size_t ws_size,
                              hipStream_t stream)
{
    (void)in_sizes; (void)n_in; (void)out_size; (void)ws_size;
    const int*   dec  = (const int*)  d_in[0];
    const float* enc  = (const float*)d_in[2];
    const float* keys = (const float*)d_in[3];
    const float* vals = (const float*)d_in[4];
    const float* emb  = (const float*)d_in[5];
    const float* Wih1 = (const float*)d_in[6];
    const float* Whh1 = (const float*)d_in[7];
    const float* b1   = (const float*)d_in[8];
    const float* Wih2 = (const float*)d_in[9];
    const float* Whh2 = (const float*)d_in[10];
    const float* b2   = (const float*)d_in[11];
    const float* Wq   = (const float*)d_in[12];
    const float* bq   = (const float*)d_in[13];
    const float* Wout = (const float*)d_in[14];
    const float* bout = (const float*)d_in[15];
    float* out = (float*)d_out;

    // workspace carve (~59 MB)
    char* p = (char*)d_ws;
    __hip_bfloat16* WoutP = (__hip_bfloat16*)p; p += (size_t)VOCP * KLOG * 2;          // 18.6 MB
    __hip_bfloat16* Alog  = (__hip_bfloat16*)p; p += (size_t)TT * BB * KLOG * 2;       // 9.4 MB
    __hip_bfloat16* Aemb  = (__hip_bfloat16*)p; p += (size_t)TT * BB * EE * 2;         // 4.2 MB
    __hip_bfloat16* H1s   = (__hip_bfloat16*)p; p += (size_t)(TT + 1) * BB * HH * 2;   // 8.45 MB
    __hip_bfloat16* H2s   = (__hip_bfloat16*)p; p += (size_t)(TT + 1) * BB * HH * 2;   // 8.45 MB
    __hip_bfloat16* CTXs  = (__hip_bfloat16*)p; p += (size_t)(TT + 1) * BB * VV * 2;   // 1.06 MB
    float* PARTs = (float*)p; p += (size_t)(TT + 1) * NBAT * 132 * 4;                  // 8.7 MB
    int* bar = (int*)p; p += 4096;
    long long* dbg = (long long*)p; p += 256;

    pack_wout  <<<dim3((KLOG + 255) / 256, VOCP), 256, 0, stream>>>(Wout, WoutP);
    init_state <<<dim3(128), 256, 0, stream>>>(enc, H1s, H2s, bar);
    gather_emb <<<dim3(TT * BB), 256, 0, stream>>>(dec, emb, Aemb);

    decoder_persistent<<<dim3(NB2), 512, 64 * KK * 2 + 64 * VV * 2, stream>>>(
        Wih1, Whh1, b1, Wih2, Whh2, b2, Wq, bq, keys, vals,
        Aemb, H1s, H2s, CTXs, PARTs, Alog, bar, dbg);

    logits_gemm<<<dim3(VOCP / 128, (BB * TT) / 128), 256, 0, stream>>>(Alog, WoutP, bout, out);

    // probes: identity = Workgroup_Size ((I+1)*64); phase = (dur - 1ms)/4.
    probe<0><<<dim3(1),  64, 0, stream>>>(dbg);
    probe<1><<<dim3(1), 128, 0, stream>>>(dbg);
    probe<2><<<dim3(1), 192, 0, stream>>>(dbg);
    probe<3><<<dim3(1), 256, 0, stream>>>(dbg);
}

// Round 17
// 4240.753 us; speedup vs baseline: 22.4841x; 6.9917x over previous
//
#include <hip/hip_runtime.h>
#include <hip/hip_bf16.h>
#include <cstddef>

// ---------------- problem constants ----------------
#define BB    32
#define T1    129
#define TT    128
#define SS    256
#define EE    512
#define HH    1024
#define KK    128
#define VV    128
#define VOC   8000
#define VOCP  8064
#define KLOG  1152          // H + V
#define NBW   128           // worker blocks
#define NBAT  128           // attention sub-blocks (4 per batch, 64 s each)
#define NB2   (NBW + NBAT)

typedef __bf16 bf16x8 __attribute__((ext_vector_type(8)));
typedef float  f32x4  __attribute__((ext_vector_type(4)));
typedef unsigned int u32x4 __attribute__((ext_vector_type(4)));
typedef int    i32x2  __attribute__((ext_vector_type(2)));

#define MFMA(a,b,c) __builtin_amdgcn_mfma_f32_16x16x32_bf16((a),(b),(c),0,0,0)
#define VMCNT0 do { asm volatile("s_waitcnt vmcnt(0)" ::: "memory"); \
                    __builtin_amdgcn_sched_barrier(0); } while (0)

// Write-through (MALL) stores; consumers use normal loads of step-indexed
// single-use addresses (reader L2 can't hold stale copies).
__device__ __forceinline__ void cstore16(const void* p, u32x4 v) {
    asm volatile("global_store_dwordx4 %0, %1, off sc0 sc1" :: "v"(p), "v"(v) : "memory");
}
__device__ __forceinline__ void cstore4i(const int* p, int v) {
    asm volatile("global_store_dword %0, %1, off sc0 sc1" :: "v"(p), "v"(v) : "memory");
}
__device__ __forceinline__ void cstore4f(const float* p, float v) {
    asm volatile("global_store_dword %0, %1, off sc0 sc1" :: "v"(p), "v"(v) : "memory");
}

// Flag polls (flags are monotonic step counters).
__device__ __forceinline__ void poll32v(const int* flags, int target, int lane)
{
    const int* p = flags + (lane & 31);
    for (;;) {
        int f;
        asm volatile("global_load_dword %0, %1, off sc0 sc1\n\ts_waitcnt vmcnt(0)"
                     : "=v"(f) : "v"(p) : "memory");
        if (__all(f >= target)) break;
        __builtin_amdgcn_s_sleep(1);
    }
}
__device__ __forceinline__ void poll128v(const int* flags, int target, int lane)
{
    const int* p = flags + lane * 2;
    for (;;) {
        i32x2 f;
        asm volatile("global_load_dwordx2 %0, %1, off sc0 sc1\n\ts_waitcnt vmcnt(0)"
                     : "=v"(f) : "v"(p) : "memory");
        if (__all(f.x >= target && f.y >= target)) break;
        __builtin_amdgcn_s_sleep(1);
    }
}
__device__ __forceinline__ void poll3v(const int* flags, int target, int lane)
{
    const int* p = flags + ((lane < 3) ? lane : 0);
    for (;;) {
        int f;
        asm volatile("global_load_dword %0, %1, off sc0 sc1\n\ts_waitcnt vmcnt(0)"
                     : "=v"(f) : "v"(p) : "memory");
        if (__all(f >= target)) break;
        __builtin_amdgcn_s_sleep(1);
    }
}

union bf8u { __hip_bfloat16 h[8]; bf16x8 v; };

__device__ __forceinline__ bf16x8 cvt8(float4 a, float4 b) {
    bf8u u;
    u.h[0] = __float2bfloat16(a.x); u.h[1] = __float2bfloat16(a.y);
    u.h[2] = __float2bfloat16(a.z); u.h[3] = __float2bfloat16(a.w);
    u.h[4] = __float2bfloat16(b.x); u.h[5] = __float2bfloat16(b.y);
    u.h[6] = __float2bfloat16(b.z); u.h[7] = __float2bfloat16(b.w);
    return u.v;
}
__device__ __forceinline__ float fsig(float x) { return 1.f / (1.f + __expf(-x)); }

// Combine 4 softmax partials for one batch, k-range [v0, v0+8) -> bf16x8.
// EXPRESSION ORDER MUST MATCH the Alog writer (bit-identical bf16).
__device__ __forceinline__ bf16x8 combine4(const float* Pt, int b4, int v0)
{
    f32x4 pva[4], pvb[4];
    float m[4], s[4];
    #pragma unroll
    for (int i = 0; i < 4; ++i) {
        const float* pp = Pt + (size_t)(b4 + i) * 132;
        pva[i] = *(const f32x4*)(pp + v0);
        pvb[i] = *(const f32x4*)(pp + v0 + 4);
        m[i] = pp[128]; s[i] = pp[129];
    }
    float M = fmaxf(fmaxf(m[0], m[1]), fmaxf(m[2], m[3]));
    float w0 = __expf(m[0] - M), w1 = __expf(m[1] - M);
    float w2 = __expf(m[2] - M), w3 = __expf(m[3] - M);
    float inv = 1.f / (w0 * s[0] + w1 * s[1] + w2 * s[2] + w3 * s[3]);
    bf8u u;
    #pragma unroll
    for (int e = 0; e < 4; ++e) {
        u.h[e]     = __float2bfloat16((w0*pva[0][e] + w1*pva[1][e] + w2*pva[2][e] + w3*pva[3][e]) * inv);
        u.h[4 + e] = __float2bfloat16((w0*pvb[0][e] + w1*pvb[1][e] + w2*pvb[2][e] + w3*pvb[3][e]) * inv);
    }
    return u.v;
}

// ---------------- prologue kernels ----------------
__global__ void pack_wout(const float* __restrict__ W, __hip_bfloat16* __restrict__ Wp)
{
    int v = blockIdx.y;
    int k = blockIdx.x * 256 + threadIdx.x;
    if (k >= KLOG) return;
    float w = (v < VOC) ? W[(size_t)v * KLOG + k] : 0.f;
    Wp[(size_t)v * KLOG + k] = __float2bfloat16(w);
}

__global__ void init_state(const float* __restrict__ enc,
                           __hip_bfloat16* __restrict__ H1s,
                           __hip_bfloat16* __restrict__ H2s,
                           int* __restrict__ bar)
{
    int i = blockIdx.x * 256 + threadIdx.x;
    if (i < 1024) bar[i] = 0;   // flag1[0:128] flag2[128:256] flagp[256:384]
    if (i >= BB * HH) return;
    __hip_bfloat16 eb = __float2bfloat16(enc[i]);
    H1s[i] = eb;   // slot 0 = h1(-1)
    H2s[i] = eb;   // slot 0 = h2(-1)
}

__global__ void gather_emb(const int* __restrict__ tok, const float* __restrict__ emb,
                           __hip_bfloat16* __restrict__ Aemb)
{
    int bid = blockIdx.x;          // t*32 + b
    int t = bid >> 5, b = bid & 31;
    int id = tok[b * T1 + t];
    const float* er = emb + (size_t)id * EE;
    __hip_bfloat16* dst = Aemb + (size_t)bid * EE;
    for (int k = threadIdx.x; k < EE; k += 256)
        dst[k] = __float2bfloat16(er[k]);
}

// ---------------- persistent decoder ----------------
// 256 blocks x 512 threads. Blocks 0..127: LSTM workers (8 hidden units each;
// they also combine attention partials in-register). Blocks 128..255:
// attention sub-blocks; a=bid-128, batch b=a>>2, s-quarter iq=a&3.
__global__ __launch_bounds__(512, 2) void decoder_persistent(
    const float* __restrict__ Wih1, const float* __restrict__ Whh1, const float* __restrict__ b1v,
    const float* __restrict__ Wih2, const float* __restrict__ Whh2, const float* __restrict__ b2v,
    const float* __restrict__ Wq,   const float* __restrict__ bq,
    const float* __restrict__ keys, const float* __restrict__ vals,
    const __hip_bfloat16* __restrict__ Aemb,
    __hip_bfloat16* H1s, __hip_bfloat16* H2s,
    float* PARTs, __hip_bfloat16* Alog, int* bar)
{
    const int bid = blockIdx.x;
    const int tid = threadIdx.x;
    const int w   = tid >> 6;
    const int cg  = w >> 2;
    const int kq  = w & 3;
    const int l   = tid & 63;
    const int l15 = l & 15, l4 = l >> 4;

    int* flag1 = bar;          // 128, h1 ready
    int* flag2 = bar + 128;    // 128, h2 ready
    int* flagp = bar + 256;    // 128, attn partial ready

    __shared__ float G[2][4][32][17];
    __shared__ alignas(16) __hip_bfloat16 hstage[32][8];
    __shared__ alignas(16) __hip_bfloat16 cstage[128];
    __shared__ alignas(16) float hs[HH];
    __shared__ float qs[KK];
    __shared__ float esl[64];
    __shared__ alignas(16) float pvl[128];
    __shared__ float red[512];
    __shared__ float wmx[4], wsm[4];

    extern __shared__ __hip_bfloat16 kvls[];                 // dynamic 32 KB
    __hip_bfloat16 (*kls)[64] = (__hip_bfloat16(*)[64])kvls;             // [KK][64]
    __hip_bfloat16 (*vls)[VV] = (__hip_bfloat16(*)[VV])(kvls + KK * 64); // [64][VV]

    if (bid < NBW) {
        // ================= WORKER =================
        const int n0 = bid * 32 + cg * 16;

        bf16x8 w1e[4], w1c, w1h[8], w2a[8], w2b[8];
        {
            const int col  = n0 + l15;
            const int orow = (col & 3) * HH + (col >> 2);   // packed rp=4j+g -> g*H+j
            #pragma unroll
            for (int s = 0; s < 4; ++s) {
                int k0 = kq * 128 + s * 32 + l4 * 8;
                const float* p0 = Wih1 + (size_t)orow * (EE + VV) + k0;
                w1e[s] = cvt8(*(const float4*)p0, *(const float4*)(p0 + 4));
            }
            {
                int k0 = kq * 32 + l4 * 8;
                const float* p0 = Wih1 + (size_t)orow * (EE + VV) + EE + k0;
                w1c = cvt8(*(const float4*)p0, *(const float4*)(p0 + 4));
            }
            #pragma unroll
            for (int s = 0; s < 8; ++s) {
                int k0 = kq * 256 + s * 32 + l4 * 8;
                const float* p1 = Whh1 + (size_t)orow * HH + k0;
                const float* p2 = Wih2 + (size_t)orow * HH + k0;
                const float* p3 = Whh2 + (size_t)orow * HH + k0;
                w1h[s] = cvt8(*(const float4*)p1, *(const float4*)(p1 + 4));
                w2a[s] = cvt8(*(const float4*)p2, *(const float4*)(p2 + 4));
                w2b[s] = cvt8(*(const float4*)p3, *(const float4*)(p3 + 4));
            }
        }

        float c1r = 0.f, c2r = 0.f;
        float gb1[4], gb2[4];
        {
            int jl = tid & 7;
            int j  = bid * 8 + jl;
            #pragma unroll
            for (int g = 0; g < 4; ++g) { gb1[g] = b1v[g * HH + j]; gb2[g] = b2v[g * HH + j]; }
        }

        // prologue pre-acc (slot-0, never overwritten; normal loads)
        f32x4 acc1A = {0,0,0,0}, acc1B = {0,0,0,0}, acc2A = {0,0,0,0}, acc2B = {0,0,0,0};
        #pragma unroll
        for (int s = 0; s < 4; ++s) {
            int k0 = kq * 128 + s * 32 + l4 * 8;
            bf16x8 a0 = *(const bf16x8*)(Aemb + (size_t)l15 * EE + k0);
            bf16x8 a1 = *(const bf16x8*)(Aemb + (size_t)(16 + l15) * EE + k0);
            acc1A = MFMA(a0, w1e[s], acc1A);
            acc1B = MFMA(a1, w1e[s], acc1B);
        }
        #pragma unroll
        for (int s = 0; s < 8; ++s) {
            int k0 = kq * 256 + s * 32 + l4 * 8;
            bf16x8 a0 = *(const bf16x8*)(H1s + (size_t)l15 * HH + k0);
            bf16x8 a1 = *(const bf16x8*)(H1s + (size_t)(16 + l15) * HH + k0);
            acc1A = MFMA(a0, w1h[s], acc1A);
            acc1B = MFMA(a1, w1h[s], acc1B);
            bf16x8 b0 = *(const bf16x8*)(H2s + (size_t)l15 * HH + k0);
            bf16x8 b1 = *(const bf16x8*)(H2s + (size_t)(16 + l15) * HH + k0);
            acc2A = MFMA(b0, w2b[s], acc2A);
            acc2B = MFMA(b1, w2b[s], acc2B);
        }

        bf16x8 fA[8], fB[8];

        #pragma unroll 1
        for (int t = 0; t < TT; ++t) {
            const int rnd = t + 1;
            __hip_bfloat16* AlogT = Alog + (size_t)t * BB * KLOG;
            const __hip_bfloat16* H1t = H1s + (size_t)rnd * BB * HH;
            const __hip_bfloat16* H2t = H2s + (size_t)rnd * BB * HH;

            // ---- S1: combine attn partials -> ctx(t-1) frag; + Wctx*ctx; cell1 ----
            if (t > 0) {
                poll128v(flagp, t, l);                         // all waves
                const float* Pt = PARTs + (size_t)t * NBAT * 132;
                int v0 = kq * 32 + l4 * 8;
                bf16x8 ca = combine4(Pt, l15 * 4, v0);
                bf16x8 cb = combine4(Pt, (16 + l15) * 4, v0);
                acc1A = MFMA(ca, w1c, acc1A);
                acc1B = MFMA(cb, w1c, acc1B);
            }
            #pragma unroll
            for (int r = 0; r < 4; ++r) {
                G[cg][kq][l4 * 4 + r][l15]      = acc1A[r];
                G[cg][kq][16 + l4 * 4 + r][l15] = acc1B[r];
            }
            acc1A = (f32x4){0,0,0,0}; acc1B = (f32x4){0,0,0,0};
            __syncthreads();
            if (tid < 256) {
                int b = tid >> 3, jl = tid & 7;
                int cg2 = jl >> 2, cb = (jl & 3) * 4;
                float g0 = G[cg2][0][b][cb+0] + G[cg2][1][b][cb+0] + G[cg2][2][b][cb+0] + G[cg2][3][b][cb+0] + gb1[0];
                float g1 = G[cg2][0][b][cb+1] + G[cg2][1][b][cb+1] + G[cg2][2][b][cb+1] + G[cg2][3][b][cb+1] + gb1[1];
                float g2 = G[cg2][0][b][cb+2] + G[cg2][1][b][cb+2] + G[cg2][2][b][cb+2] + G[cg2][3][b][cb+2] + gb1[2];
                float g3 = G[cg2][0][b][cb+3] + G[cg2][1][b][cb+3] + G[cg2][2][b][cb+3] + G[cg2][3][b][cb+3] + gb1[3];
                c1r = fsig(g1) * c1r + fsig(g0) * tanhf(g2);
                float h = fsig(g3) * tanhf(c1r);
                hstage[b][jl] = __float2bfloat16(h);
            }
            __syncthreads();
            if (w == 0) {
                if (l < 32)
                    cstore16((void*)(H1t + (size_t)l * HH + bid * 8), *(const u32x4*)&hstage[l][0]);
                VMCNT0;
                if (l == 0) cstore4i(&flag1[bid], rnd);
            }
            poll32v(flag1 + kq * 32, rnd, l);                  // my k-slice producers

            // ---- S2 ----
            #pragma unroll
            for (int s = 0; s < 8; ++s) {
                int k0 = kq * 256 + s * 32 + l4 * 8;
                fA[s] = *(const bf16x8*)(H1t + (size_t)l15 * HH + k0);
                fB[s] = *(const bf16x8*)(H1t + (size_t)(16 + l15) * HH + k0);
            }
            #pragma unroll
            for (int s = 0; s < 8; ++s) {
                acc2A = MFMA(fA[s], w2a[s], acc2A);
                acc2B = MFMA(fB[s], w2a[s], acc2B);
                acc1A = MFMA(fA[s], w1h[s], acc1A);
                acc1B = MFMA(fB[s], w1h[s], acc1B);
            }
            #pragma unroll
            for (int r = 0; r < 4; ++r) {
                G[cg][kq][l4 * 4 + r][l15]      = acc2A[r];
                G[cg][kq][16 + l4 * 4 + r][l15] = acc2B[r];
            }
            acc2A = (f32x4){0,0,0,0}; acc2B = (f32x4){0,0,0,0};
            __syncthreads();
            if (tid < 256) {
                int b = tid >> 3, jl = tid & 7;
                int cg2 = jl >> 2, cb = (jl & 3) * 4;
                float g0 = G[cg2][0][b][cb+0] + G[cg2][1][b][cb+0] + G[cg2][2][b][cb+0] + G[cg2][3][b][cb+0] + gb2[0];
                float g1 = G[cg2][0][b][cb+1] + G[cg2][1][b][cb+1] + G[cg2][2][b][cb+1] + G[cg2][3][b][cb+1] + gb2[1];
                float g2 = G[cg2][0][b][cb+2] + G[cg2][1][b][cb+2] + G[cg2][2][b][cb+2] + G[cg2][3][b][cb+2] + gb2[2];
                float g3 = G[cg2][0][b][cb+3] + G[cg2][1][b][cb+3] + G[cg2][2][b][cb+3] + G[cg2][3][b][cb+3] + gb2[3];
                c2r = fsig(g1) * c2r + fsig(g0) * tanhf(g2);
                float h = fsig(g3) * tanhf(c2r);
                hstage[tid >> 3][tid & 7] = __float2bfloat16(h);
            }
            __syncthreads();
            if (w == 0) {
                if (l < 32) {
                    u32x4 v = *(const u32x4*)&hstage[l][0];
                    cstore16((void*)(H2t + (size_t)l * HH + bid * 8), v);
                    *(u32x4*)(AlogT + (size_t)l * KLOG + bid * 8) = v;   // normal store
                }
                VMCNT0;
                if (l == 0) cstore4i(&flag2[bid], rnd);
            }
            poll32v(flag2 + kq * 32, rnd, l);

            // ---- S3: pre-acc gates2(t+1) += Whh2*h2(t); + emb(t+1) ----
            #pragma unroll
            for (int s = 0; s < 8; ++s) {
                int k0 = kq * 256 + s * 32 + l4 * 8;
                fA[s] = *(const bf16x8*)(H2t + (size_t)l15 * HH + k0);
                fB[s] = *(const bf16x8*)(H2t + (size_t)(16 + l15) * HH + k0);
            }
            #pragma unroll
            for (int s = 0; s < 8; ++s) {
                acc2A = MFMA(fA[s], w2b[s], acc2A);
                acc2B = MFMA(fB[s], w2b[s], acc2B);
            }
            if (t + 1 < TT) {
                const __hip_bfloat16* An = Aemb + (size_t)(t + 1) * BB * EE;
                #pragma unroll
                for (int s = 0; s < 4; ++s) {
                    int k0 = kq * 128 + s * 32 + l4 * 8;
                    bf16x8 a0 = *(const bf16x8*)(An + (size_t)l15 * EE + k0);
                    bf16x8 a1 = *(const bf16x8*)(An + (size_t)(16 + l15) * EE + k0);
                    acc1A = MFMA(a0, w1e[s], acc1A);
                    acc1B = MFMA(a1, w1e[s], acc1B);
                }
            }
        }

    } else {
        // ================= ATTENTION sub-block =================
        const int a  = bid - NBW;      // 0..127
        const int b  = a >> 2;         // batch
        const int iq = a & 3;          // s-quarter
        const int s0 = iq * 64;

        // K/V quarter -> LDS (bf16), once
        for (int i = tid; i < 64 * KK; i += 512) {
            int sl = i >> 7, k = i & 127;
            kls[k][sl] = __float2bfloat16(keys[((size_t)b * SS + s0 + sl) * KK + k]);
            vls[sl][k] = __float2bfloat16(vals[((size_t)b * SS + s0 + sl) * VV + k]);
        }
        // Wq -> registers: thread (kp=tid>>2, qc=tid&3) holds Wq[kp][qc*256..+256)
        const int kp = tid >> 2, qc = tid & 3;
        bf16x8 wq[32];
        {
            const float* src = Wq + (size_t)kp * HH + qc * 256;
            #pragma unroll
            for (int c = 0; c < 32; ++c)
                wq[c] = cvt8(*(const float4*)(src + c * 8), *(const float4*)(src + c * 8 + 4));
        }
        float bqr = bq[kp];
        __syncthreads();

        #pragma unroll 1
        for (int t = 0; t < TT; ++t) {
            const int rnd = t + 1;
            __hip_bfloat16* AlogT = Alog + (size_t)t * BB * KLOG;
            const __hip_bfloat16* H2t = H2s + (size_t)rnd * BB * HH;
            float* PARTt = PARTs + (size_t)rnd * NBAT * 132;

            if (w == 0) poll128v(flag2, rnd, l);
            __syncthreads();

            // h2[b] -> fp32 LDS
            bf16x8 hrow;
            if (tid < 128)
                hrow = *(const bf16x8*)(H2t + (size_t)b * HH + tid * 8);
            if (tid < 128) {
                #pragma unroll
                for (int e = 0; e < 8; ++e) hs[tid * 8 + e] = (float)hrow[e];
            }
            __syncthreads();
            {   // q[kp] from register Wq
                const float* hh = hs + qc * 256;
                float acc = 0.f;
                #pragma unroll
                for (int c = 0; c < 32; ++c) {
                    bf16x8 wv = wq[c];
                    #pragma unroll
                    for (int e = 0; e < 8; ++e) acc += (float)wv[e] * hh[c * 8 + e];
                }
                acc += __shfl_xor(acc, 1);
                acc += __shfl_xor(acc, 2);
                if (qc == 0) qs[kp] = acc + bqr;
            }
            __syncthreads();
            // energy for 64 s: sl=tid>>2, kc=tid&3 (32 k each)
            if (tid < 256) {
                int sl = tid >> 2, kc = tid & 3;
                float acc = 0.f;
                #pragma unroll 8
                for (int c = 0; c < 32; ++c) {
                    int k = kc * 32 + c;
                    acc += __bfloat162float(kls[k][sl]) * qs[k];
                }
                acc += __shfl_xor(acc, 1);
                acc += __shfl_xor(acc, 2);
                if (kc == 0) esl[sl] = acc;
            }
            __syncthreads();
            // local softmax over 64 (wave 0)
            if (w == 0) {
                float e2 = esl[l];
                float m = e2;
                #pragma unroll
                for (int off = 32; off > 0; off >>= 1)
                    m = fmaxf(m, __shfl_xor(m, off));
                float pp = __expf(e2 - m);
                esl[l] = pp;
                float sm = pp;
                #pragma unroll
                for (int off = 32; off > 0; off >>= 1)
                    sm += __shfl_xor(sm, off);
                if (l == 0) { wmx[0] = m; wsm[0] = sm; }
            }
            __syncthreads();
            // PV partial: v=tid&127, sh=tid>>7 handles 16 s
            {
                int v = tid & 127, sh = tid >> 7;
                float acc = 0.f;
                #pragma unroll 4
                for (int i2 = 0; i2 < 16; ++i2) {
                    int sl = sh * 16 + i2;
                    acc += esl[sl] * __bfloat162float(vls[sl][v]);
                }
                red[tid] = acc;
            }
            __syncthreads();
            if (tid < 128)
                pvl[tid] = red[tid] + red[tid + 128] + red[tid + 256] + red[tid + 384];
            __syncthreads();

            // publish partial (pv[128], m, sum) write-through + flag
            if (w == 0) {
                float* dst = PARTt + (size_t)a * 132;
                if (l < 32)
                    cstore16((void*)(dst + l * 4), *(const u32x4*)&pvl[l * 4]);
                if (l == 32) { cstore4f(dst + 128, wmx[0]); cstore4f(dst + 129, wsm[0]); }
                VMCNT0;
                if (l == 0) cstore4i(&flagp[a], rnd);
            }

            // iq==0: off-critical-path combine -> Alog ctx (normal stores)
            if (iq == 0) {
                if (w == 0) poll3v(flagp + a + 1, rnd, l);
                __syncthreads();
                if (tid < 16) {
                    const float* Pt = PARTs + (size_t)rnd * NBAT * 132;
                    bf16x8 cv = combine4(Pt, a, tid * 8);
                    bf8u u; u.v = cv;
                    *(u32x4*)(AlogT + (size_t)b * KLOG + HH + tid * 8) = *(const u32x4*)&u.h[0];
                }
            }
        }
    }
}

// ---------------- deferred logits GEMM ----------------
__global__ __launch_bounds__(256) void logits_gemm(
    const __hip_bfloat16* __restrict__ Alog,
    const __hip_bfloat16* __restrict__ W,
    const float* __restrict__ bout,
    float* __restrict__ out)
{
    int n0 = blockIdx.x * 128;
    int m0 = blockIdx.y * 128;
    int wv = threadIdx.x >> 6, l = threadIdx.x & 63;
    int l15 = l & 15, l4 = l >> 4;

    f32x4 acc[8][2] = {};
    const __hip_bfloat16* Ap = Alog + (size_t)(m0 + l15) * KLOG + l4 * 8;
    const __hip_bfloat16* Bp = W    + (size_t)(n0 + wv * 32 + l15) * KLOG + l4 * 8;

    for (int kt = 0; kt < KLOG; kt += 32) {
        bf16x8 b0 = *(const bf16x8*)(Bp + kt);
        bf16x8 b1 = *(const bf16x8*)(Bp + (size_t)16 * KLOG + kt);
        #pragma unroll
        for (int ms = 0; ms < 8; ++ms) {
            bf16x8 a = *(const bf16x8*)(Ap + (size_t)ms * 16 * KLOG + kt);
            acc[ms][0] = MFMA(a, b0, acc[ms][0]);
            acc[ms][1] = MFMA(a, b1, acc[ms][1]);
        }
    }
    #pragma unroll
    for (int ms = 0; ms < 8; ++ms)
        #pragma unroll
        for (int ns = 0; ns < 2; ++ns) {
            int col = n0 + wv * 32 + ns * 16 + l15;
            if (col < VOC) {
                float bias = bout[col];
                #pragma unroll
                for (int r = 0; r < 4; ++r) {
                    int m = m0 + ms * 16 + l4 * 4 + r;
                    int b = m & 31, t = m >> 5;
                    out[((size_t)b * TT + t) * VOC + col] = acc[ms][ns][r] + bias;
                }
            }
        }
}

// ---------------- host ----------------
extern "C" void kernel_launch(void* const* d_in, const int* in_sizes, int n_in,
                              void* d_out, int out_size, void* d_ws, size_t ws_size,
                              hipStream_t stream)
{
    (void)in_sizes; (void)n_in; (void)out_size; (void)ws_size;
    const int*   dec  = (const int*)  d_in[0];
    const float* enc  = (const float*)d_in[2];
    const float* keys = (const float*)d_in[3];
    const float* vals = (const float*)d_in[4];
    const float* emb  = (const float*)d_in[5];
    const float* Wih1 = (const float*)d_in[6];
    const float* Whh1 = (const float*)d_in[7];
    const float* b1   = (const float*)d_in[8];
    const float* Wih2 = (const float*)d_in[9];
    const float* Whh2 = (const float*)d_in[10];
    const float* b2   = (const float*)d_in[11];
    const float* Wq   = (const float*)d_in[12];
    const float* bq   = (const float*)d_in[13];
    const float* Wout = (const float*)d_in[14];
    const float* bout = (const float*)d_in[15];
    float* out = (float*)d_out;

    // workspace carve (~58 MB)
    char* p = (char*)d_ws;
    __hip_bfloat16* WoutP = (__hip_bfloat16*)p; p += (size_t)VOCP * KLOG * 2;          // 18.6 MB
    __hip_bfloat16* Alog  = (__hip_bfloat16*)p; p += (size_t)TT * BB * KLOG * 2;       // 9.4 MB
    __hip_bfloat16* Aemb  = (__hip_bfloat16*)p; p += (size_t)TT * BB * EE * 2;         // 4.2 MB
    __hip_bfloat16* H1s   = (__hip_bfloat16*)p; p += (size_t)(TT + 1) * BB * HH * 2;   // 8.45 MB
    __hip_bfloat16* H2s   = (__hip_bfloat16*)p; p += (size_t)(TT + 1) * BB * HH * 2;   // 8.45 MB
    float* PARTs = (float*)p; p += (size_t)(TT + 1) * NBAT * 132 * 4;                  // 8.7 MB
    int* bar = (int*)p; p += 4096;

    pack_wout  <<<dim3((KLOG + 255) / 256, VOCP), 256, 0, stream>>>(Wout, WoutP);
    init_state <<<dim3(128), 256, 0, stream>>>(enc, H1s, H2s, bar);
    gather_emb <<<dim3(TT * BB), 256, 0, stream>>>(dec, emb, Aemb);

    decoder_persistent<<<dim3(NB2), 512, 64 * KK * 2 + 64 * VV * 2, stream>>>(
        Wih1, Whh1, b1, Wih2, Whh2, b2, Wq, bq, keys, vals,
        Aemb, H1s, H2s, PARTs, Alog, bar);

    logits_gemm<<<dim3(VOCP / 128, (BB * TT) / 128), 256, 0, stream>>>(Alog, WoutP, bout, out);
}

// Round 18
// 4129.293 us; speedup vs baseline: 23.0910x; 1.0270x over previous
//
#include <hip/hip_runtime.h>
#include <hip/hip_bf16.h>
#include <cstddef>

// ---------------- problem constants ----------------
#define BB    32
#define T1    129
#define TT    128
#define SS    256
#define EE    512
#define HH    1024
#define KK    128
#define VV    128
#define VOC   8000
#define VOCP  8064
#define KLOG  1152          // H + V
#define NBW   128           // worker blocks
#define NBA   32            // attention blocks (full S each)
#define NB2   (NBW + NBA)   // 160 blocks -> 1 block/CU (no co-residency)

typedef __bf16 bf16x8 __attribute__((ext_vector_type(8)));
typedef float  f32x4  __attribute__((ext_vector_type(4)));
typedef unsigned int u32x4 __attribute__((ext_vector_type(4)));
typedef int    i32x2  __attribute__((ext_vector_type(2)));

#define MFMA(a,b,c) __builtin_amdgcn_mfma_f32_16x16x32_bf16((a),(b),(c),0,0,0)
#define VMCNT0 do { asm volatile("s_waitcnt vmcnt(0)" ::: "memory"); \
                    __builtin_amdgcn_sched_barrier(0); } while (0)

// Write-through (MALL) stores; consumers use normal loads of step-indexed
// single-use addresses (reader L2 can't hold stale copies).
__device__ __forceinline__ void cstore16(const void* p, u32x4 v) {
    asm volatile("global_store_dwordx4 %0, %1, off sc0 sc1" :: "v"(p), "v"(v) : "memory");
}
__device__ __forceinline__ void cstore4i(const int* p, int v) {
    asm volatile("global_store_dword %0, %1, off sc0 sc1" :: "v"(p), "v"(v) : "memory");
}

// Flag polls (flags are monotonic step counters).
__device__ __forceinline__ void poll32v(const int* flags, int target, int lane)
{
    const int* p = flags + (lane & 31);
    for (;;) {
        int f;
        asm volatile("global_load_dword %0, %1, off sc0 sc1\n\ts_waitcnt vmcnt(0)"
                     : "=v"(f) : "v"(p) : "memory");
        if (__all(f >= target)) break;
        __builtin_amdgcn_s_sleep(1);
    }
}
__device__ __forceinline__ void poll128v(const int* flags, int target, int lane)
{
    const int* p = flags + lane * 2;
    for (;;) {
        i32x2 f;
        asm volatile("global_load_dwordx2 %0, %1, off sc0 sc1\n\ts_waitcnt vmcnt(0)"
                     : "=v"(f) : "v"(p) : "memory");
        if (__all(f.x >= target && f.y >= target)) break;
        __builtin_amdgcn_s_sleep(1);
    }
}

union bf8u { __hip_bfloat16 h[8]; bf16x8 v; };

__device__ __forceinline__ bf16x8 cvt8(float4 a, float4 b) {
    bf8u u;
    u.h[0] = __float2bfloat16(a.x); u.h[1] = __float2bfloat16(a.y);
    u.h[2] = __float2bfloat16(a.z); u.h[3] = __float2bfloat16(a.w);
    u.h[4] = __float2bfloat16(b.x); u.h[5] = __float2bfloat16(b.y);
    u.h[6] = __float2bfloat16(b.z); u.h[7] = __float2bfloat16(b.w);
    return u.v;
}
__device__ __forceinline__ float fsig(float x) { return 1.f / (1.f + __expf(-x)); }

// Normalized-ctx fragment (f32 partial -> bf16x8). Same conversion expression
// as the attention block's Alog writer -> bit-identical bf16.
__device__ __forceinline__ bf16x8 ctxfrag(const float* Pt, int row, int v0)
{
    const float* pp = Pt + (size_t)row * 128 + v0;
    f32x4 a = *(const f32x4*)pp;
    f32x4 b = *(const f32x4*)(pp + 4);
    bf8u u;
    #pragma unroll
    for (int e = 0; e < 4; ++e) {
        u.h[e]     = __float2bfloat16(a[e]);
        u.h[4 + e] = __float2bfloat16(b[e]);
    }
    return u.v;
}

// ---------------- prologue kernels ----------------
__global__ void pack_wout(const float* __restrict__ W, __hip_bfloat16* __restrict__ Wp)
{
    int v = blockIdx.y;
    int k = blockIdx.x * 256 + threadIdx.x;
    if (k >= KLOG) return;
    float w = (v < VOC) ? W[(size_t)v * KLOG + k] : 0.f;
    Wp[(size_t)v * KLOG + k] = __float2bfloat16(w);
}

__global__ void init_state(const float* __restrict__ enc,
                           __hip_bfloat16* __restrict__ H1s,
                           __hip_bfloat16* __restrict__ H2s,
                           int* __restrict__ bar)
{
    int i = blockIdx.x * 256 + threadIdx.x;
    if (i < 1024) bar[i] = 0;   // flag1[0:128] flag2[128:256] flagp[256:288]
    if (i >= BB * HH) return;
    __hip_bfloat16 eb = __float2bfloat16(enc[i]);
    H1s[i] = eb;   // slot 0 = h1(-1)
    H2s[i] = eb;   // slot 0 = h2(-1)
}

__global__ void gather_emb(const int* __restrict__ tok, const float* __restrict__ emb,
                           __hip_bfloat16* __restrict__ Aemb)
{
    int bid = blockIdx.x;          // t*32 + b
    int t = bid >> 5, b = bid & 31;
    int id = tok[b * T1 + t];
    const float* er = emb + (size_t)id * EE;
    __hip_bfloat16* dst = Aemb + (size_t)bid * EE;
    for (int k = threadIdx.x; k < EE; k += 256)
        dst[k] = __float2bfloat16(er[k]);
}

// ---------------- persistent decoder ----------------
// 160 blocks x 512 threads, 1 block/CU. Blocks 0..127: LSTM workers
// (8 hidden units each; convert normalized ctx partials in-register).
// Blocks 128..159: dedicated attention, batch b = bid-128, full S in LDS,
// Wq in registers; publish normalized ctx as f32 (write-through).
__global__ __launch_bounds__(512, 2) void decoder_persistent(
    const float* __restrict__ Wih1, const float* __restrict__ Whh1, const float* __restrict__ b1v,
    const float* __restrict__ Wih2, const float* __restrict__ Whh2, const float* __restrict__ b2v,
    const float* __restrict__ Wq,   const float* __restrict__ bq,
    const float* __restrict__ keys, const float* __restrict__ vals,
    const __hip_bfloat16* __restrict__ Aemb,
    __hip_bfloat16* H1s, __hip_bfloat16* H2s,
    float* PARTs, __hip_bfloat16* Alog, int* bar)
{
    const int bid = blockIdx.x;
    const int tid = threadIdx.x;
    const int w   = tid >> 6;
    const int cg  = w >> 2;
    const int kq  = w & 3;
    const int l   = tid & 63;
    const int l15 = l & 15, l4 = l >> 4;

    int* flag1 = bar;          // 128, h1 ready
    int* flag2 = bar + 128;    // 128, h2 ready
    int* flagp = bar + 256;    // 32,  normalized ctx partial ready

    __shared__ float G[2][4][32][17];
    __shared__ alignas(16) __hip_bfloat16 hstage[32][8];
    __shared__ alignas(16) float hs[HH];
    __shared__ float qs[KK];
    __shared__ float esl[SS];
    __shared__ alignas(16) float pvl[128];
    __shared__ float red[512];
    __shared__ float wmx[4], wsm[4];

    extern __shared__ __hip_bfloat16 kvls[];                 // dynamic 128 KB
    __hip_bfloat16 (*kls)[SS] = (__hip_bfloat16(*)[SS])kvls;             // [KK][SS]
    __hip_bfloat16 (*vls)[VV] = (__hip_bfloat16(*)[VV])(kvls + KK * SS); // [SS][VV]

    if (bid < NBW) {
        // ================= WORKER =================
        const int n0 = bid * 32 + cg * 16;

        bf16x8 w1e[4], w1c, w1h[8], w2a[8], w2b[8];
        {
            const int col  = n0 + l15;
            const int orow = (col & 3) * HH + (col >> 2);   // packed rp=4j+g -> g*H+j
            #pragma unroll
            for (int s = 0; s < 4; ++s) {
                int k0 = kq * 128 + s * 32 + l4 * 8;
                const float* p0 = Wih1 + (size_t)orow * (EE + VV) + k0;
                w1e[s] = cvt8(*(const float4*)p0, *(const float4*)(p0 + 4));
            }
            {
                int k0 = kq * 32 + l4 * 8;
                const float* p0 = Wih1 + (size_t)orow * (EE + VV) + EE + k0;
                w1c = cvt8(*(const float4*)p0, *(const float4*)(p0 + 4));
            }
            #pragma unroll
            for (int s = 0; s < 8; ++s) {
                int k0 = kq * 256 + s * 32 + l4 * 8;
                const float* p1 = Whh1 + (size_t)orow * HH + k0;
                const float* p2 = Wih2 + (size_t)orow * HH + k0;
                const float* p3 = Whh2 + (size_t)orow * HH + k0;
                w1h[s] = cvt8(*(const float4*)p1, *(const float4*)(p1 + 4));
                w2a[s] = cvt8(*(const float4*)p2, *(const float4*)(p2 + 4));
                w2b[s] = cvt8(*(const float4*)p3, *(const float4*)(p3 + 4));
            }
        }

        float c1r = 0.f, c2r = 0.f;
        float gb1[4], gb2[4];
        {
            int jl = tid & 7;
            int j  = bid * 8 + jl;
            #pragma unroll
            for (int g = 0; g < 4; ++g) { gb1[g] = b1v[g * HH + j]; gb2[g] = b2v[g * HH + j]; }
        }

        // prologue pre-acc (slot-0, never overwritten; normal loads)
        f32x4 acc1A = {0,0,0,0}, acc1B = {0,0,0,0}, acc2A = {0,0,0,0}, acc2B = {0,0,0,0};
        #pragma unroll
        for (int s = 0; s < 4; ++s) {
            int k0 = kq * 128 + s * 32 + l4 * 8;
            bf16x8 a0 = *(const bf16x8*)(Aemb + (size_t)l15 * EE + k0);
            bf16x8 a1 = *(const bf16x8*)(Aemb + (size_t)(16 + l15) * EE + k0);
            acc1A = MFMA(a0, w1e[s], acc1A);
            acc1B = MFMA(a1, w1e[s], acc1B);
        }
        #pragma unroll
        for (int s = 0; s < 8; ++s) {
            int k0 = kq * 256 + s * 32 + l4 * 8;
            bf16x8 a0 = *(const bf16x8*)(H1s + (size_t)l15 * HH + k0);
            bf16x8 a1 = *(const bf16x8*)(H1s + (size_t)(16 + l15) * HH + k0);
            acc1A = MFMA(a0, w1h[s], acc1A);
            acc1B = MFMA(a1, w1h[s], acc1B);
            bf16x8 b0 = *(const bf16x8*)(H2s + (size_t)l15 * HH + k0);
            bf16x8 b1 = *(const bf16x8*)(H2s + (size_t)(16 + l15) * HH + k0);
            acc2A = MFMA(b0, w2b[s], acc2A);
            acc2B = MFMA(b1, w2b[s], acc2B);
        }

        bf16x8 fA[8], fB[8];

        #pragma unroll 1
        for (int t = 0; t < TT; ++t) {
            const int rnd = t + 1;
            __hip_bfloat16* AlogT = Alog + (size_t)t * BB * KLOG;
            const __hip_bfloat16* H1t = H1s + (size_t)rnd * BB * HH;
            const __hip_bfloat16* H2t = H2s + (size_t)rnd * BB * HH;

            // ---- S1: ctx(t-1) from normalized partials; + Wctx*ctx; cell1 ----
            if (t > 0) {
                poll32v(flagp, t, l);                         // all waves, 32 flags
                const float* Pt = PARTs + (size_t)t * BB * 128;
                int v0 = kq * 32 + l4 * 8;
                bf16x8 ca = ctxfrag(Pt, l15, v0);
                bf16x8 cb = ctxfrag(Pt, 16 + l15, v0);
                acc1A = MFMA(ca, w1c, acc1A);
                acc1B = MFMA(cb, w1c, acc1B);
            }
            #pragma unroll
            for (int r = 0; r < 4; ++r) {
                G[cg][kq][l4 * 4 + r][l15]      = acc1A[r];
                G[cg][kq][16 + l4 * 4 + r][l15] = acc1B[r];
            }
            acc1A = (f32x4){0,0,0,0}; acc1B = (f32x4){0,0,0,0};
            __syncthreads();
            if (tid < 256) {
                int b = tid >> 3, jl = tid & 7;
                int cg2 = jl >> 2, cb = (jl & 3) * 4;
                float g0 = G[cg2][0][b][cb+0] + G[cg2][1][b][cb+0] + G[cg2][2][b][cb+0] + G[cg2][3][b][cb+0] + gb1[0];
                float g1 = G[cg2][0][b][cb+1] + G[cg2][1][b][cb+1] + G[cg2][2][b][cb+1] + G[cg2][3][b][cb+1] + gb1[1];
                float g2 = G[cg2][0][b][cb+2] + G[cg2][1][b][cb+2] + G[cg2][2][b][cb+2] + G[cg2][3][b][cb+2] + gb1[2];
                float g3 = G[cg2][0][b][cb+3] + G[cg2][1][b][cb+3] + G[cg2][2][b][cb+3] + G[cg2][3][b][cb+3] + gb1[3];
                c1r = fsig(g1) * c1r + fsig(g0) * tanhf(g2);
                float h = fsig(g3) * tanhf(c1r);
                hstage[b][jl] = __float2bfloat16(h);
            }
            __syncthreads();
            if (w == 0) {
                if (l < 32)
                    cstore16((void*)(H1t + (size_t)l * HH + bid * 8), *(const u32x4*)&hstage[l][0]);
                VMCNT0;
                if (l == 0) cstore4i(&flag1[bid], rnd);
            }
            poll32v(flag1 + kq * 32, rnd, l);                  // my k-slice producers

            // ---- S2 ----
            #pragma unroll
            for (int s = 0; s < 8; ++s) {
                int k0 = kq * 256 + s * 32 + l4 * 8;
                fA[s] = *(const bf16x8*)(H1t + (size_t)l15 * HH + k0);
                fB[s] = *(const bf16x8*)(H1t + (size_t)(16 + l15) * HH + k0);
            }
            #pragma unroll
            for (int s = 0; s < 8; ++s) {
                acc2A = MFMA(fA[s], w2a[s], acc2A);
                acc2B = MFMA(fB[s], w2a[s], acc2B);
                acc1A = MFMA(fA[s], w1h[s], acc1A);
                acc1B = MFMA(fB[s], w1h[s], acc1B);
            }
            #pragma unroll
            for (int r = 0; r < 4; ++r) {
                G[cg][kq][l4 * 4 + r][l15]      = acc2A[r];
                G[cg][kq][16 + l4 * 4 + r][l15] = acc2B[r];
            }
            acc2A = (f32x4){0,0,0,0}; acc2B = (f32x4){0,0,0,0};
            __syncthreads();
            if (tid < 256) {
                int b = tid >> 3, jl = tid & 7;
                int cg2 = jl >> 2, cb = (jl & 3) * 4;
                float g0 = G[cg2][0][b][cb+0] + G[cg2][1][b][cb+0] + G[cg2][2][b][cb+0] + G[cg2][3][b][cb+0] + gb2[0];
                float g1 = G[cg2][0][b][cb+1] + G[cg2][1][b][cb+1] + G[cg2][2][b][cb+1] + G[cg2][3][b][cb+1] + gb2[1];
                float g2 = G[cg2][0][b][cb+2] + G[cg2][1][b][cb+2] + G[cg2][2][b][cb+2] + G[cg2][3][b][cb+2] + gb2[2];
                float g3 = G[cg2][0][b][cb+3] + G[cg2][1][b][cb+3] + G[cg2][2][b][cb+3] + G[cg2][3][b][cb+3] + gb2[3];
                c2r = fsig(g1) * c2r + fsig(g0) * tanhf(g2);
                float h = fsig(g3) * tanhf(c2r);
                hstage[tid >> 3][tid & 7] = __float2bfloat16(h);
            }
            __syncthreads();
            if (w == 0) {
                if (l < 32) {
                    u32x4 v = *(const u32x4*)&hstage[l][0];
                    cstore16((void*)(H2t + (size_t)l * HH + bid * 8), v);
                    *(u32x4*)(AlogT + (size_t)l * KLOG + bid * 8) = v;   // normal store
                }
                VMCNT0;
                if (l == 0) cstore4i(&flag2[bid], rnd);
            }
            poll32v(flag2 + kq * 32, rnd, l);

            // ---- S3: pre-acc gates2(t+1) += Whh2*h2(t); + emb(t+1) ----
            #pragma unroll
            for (int s = 0; s < 8; ++s) {
                int k0 = kq * 256 + s * 32 + l4 * 8;
                fA[s] = *(const bf16x8*)(H2t + (size_t)l15 * HH + k0);
                fB[s] = *(const bf16x8*)(H2t + (size_t)(16 + l15) * HH + k0);
            }
            #pragma unroll
            for (int s = 0; s < 8; ++s) {
                acc2A = MFMA(fA[s], w2b[s], acc2A);
                acc2B = MFMA(fB[s], w2b[s], acc2B);
            }
            if (t + 1 < TT) {
                const __hip_bfloat16* An = Aemb + (size_t)(t + 1) * BB * EE;
                #pragma unroll
                for (int s = 0; s < 4; ++s) {
                    int k0 = kq * 128 + s * 32 + l4 * 8;
                    bf16x8 a0 = *(const bf16x8*)(An + (size_t)l15 * EE + k0);
                    bf16x8 a1 = *(const bf16x8*)(An + (size_t)(16 + l15) * EE + k0);
                    acc1A = MFMA(a0, w1e[s], acc1A);
                    acc1B = MFMA(a1, w1e[s], acc1B);
                }
            }
        }

    } else {
        // ================= ATTENTION (b = bid - 128, full S) =================
        const int b = bid - NBW;

        // keys/vals -> LDS (bf16), once
        for (int i = tid; i < SS * KK; i += 512) {
            int s = i >> 7, k = i & 127;
            kls[k][s] = __float2bfloat16(keys[((size_t)b * SS + s) * KK + k]);
            vls[s][k] = __float2bfloat16(vals[((size_t)b * SS + s) * VV + k]);
        }
        // Wq -> registers: thread (kp=tid>>2, qc=tid&3) holds Wq[kp][qc*256..+256)
        const int kp = tid >> 2, qc = tid & 3;
        bf16x8 wq[32];
        {
            const float* src = Wq + (size_t)kp * HH + qc * 256;
            #pragma unroll
            for (int c = 0; c < 32; ++c)
                wq[c] = cvt8(*(const float4*)(src + c * 8), *(const float4*)(src + c * 8 + 4));
        }
        float bqr = bq[kp];
        __syncthreads();

        #pragma unroll 1
        for (int t = 0; t < TT; ++t) {
            const int rnd = t + 1;
            __hip_bfloat16* AlogT = Alog + (size_t)t * BB * KLOG;
            const __hip_bfloat16* H2t = H2s + (size_t)rnd * BB * HH;
            float* PARTt = PARTs + (size_t)rnd * BB * 128;

            if (w == 0) poll128v(flag2, rnd, l);
            __syncthreads();

            // h2[b] -> fp32 LDS
            bf16x8 hrow;
            if (tid < 128)
                hrow = *(const bf16x8*)(H2t + (size_t)b * HH + tid * 8);
            if (tid < 128) {
                #pragma unroll
                for (int e = 0; e < 8; ++e) hs[tid * 8 + e] = (float)hrow[e];
            }
            __syncthreads();
            {   // q[kp] from register Wq
                const float* hh = hs + qc * 256;
                float acc = 0.f;
                #pragma unroll
                for (int c = 0; c < 32; ++c) {
                    bf16x8 wv = wq[c];
                    #pragma unroll
                    for (int e = 0; e < 8; ++e) acc += (float)wv[e] * hh[c * 8 + e];
                }
                acc += __shfl_xor(acc, 1);
                acc += __shfl_xor(acc, 2);
                if (qc == 0) qs[kp] = acc + bqr;
            }
            __syncthreads();
            float en = 0.f;
            if (tid < SS) {             // full 128-dot per thread
                #pragma unroll 8
                for (int k = 0; k < KK; ++k)
                    en += __bfloat162float(kls[k][tid]) * qs[k];
            }
            if (w < 4) {
                float m = en;
                #pragma unroll
                for (int off = 32; off > 0; off >>= 1)
                    m = fmaxf(m, __shfl_xor(m, off));
                if (l == 0) wmx[w] = m;
            }
            __syncthreads();
            float mx = fmaxf(fmaxf(wmx[0], wmx[1]), fmaxf(wmx[2], wmx[3]));
            if (w < 4) {
                float p = __expf(en - mx);
                esl[tid] = p;
                float sm = p;
                #pragma unroll
                for (int off = 32; off > 0; off >>= 1)
                    sm += __shfl_xor(sm, off);
                if (l == 0) wsm[w] = sm;
            }
            __syncthreads();
            float inv = 1.f / (wsm[0] + wsm[1] + wsm[2] + wsm[3]);
            {   // PV: v=tid&127, sh=tid>>7 over s-quarters
                int v = tid & 127, sh = tid >> 7;
                float acc = 0.f;
                #pragma unroll 4
                for (int i2 = 0; i2 < 64; ++i2)
                    acc += esl[sh * 64 + i2] * __bfloat162float(vls[sh * 64 + i2][v]);
                red[tid] = acc;
            }
            __syncthreads();
            if (tid < 128)
                pvl[tid] = (red[tid] + red[tid + 128] + red[tid + 256] + red[tid + 384]) * inv;
            __syncthreads();

            // publish normalized ctx f32 (write-through) + flag; Alog bf16 (normal)
            if (w == 0) {
                if (l < 32)
                    cstore16((void*)(PARTt + (size_t)b * 128 + l * 4), *(const u32x4*)&pvl[l * 4]);
                VMCNT0;
                if (l == 0) cstore4i(&flagp[b], rnd);
            }
            if (tid < 16) {
                bf8u u;
                #pragma unroll
                for (int e = 0; e < 8; ++e)
                    u.h[e] = __float2bfloat16(pvl[tid * 8 + e]);
                *(u32x4*)(AlogT + (size_t)b * KLOG + HH + tid * 8) = *(const u32x4*)&u.h[0];
            }
        }
    }
}

// ---------------- deferred logits GEMM ----------------
__global__ __launch_bounds__(256) void logits_gemm(
    const __hip_bfloat16* __restrict__ Alog,
    const __hip_bfloat16* __restrict__ W,
    const float* __restrict__ bout,
    float* __restrict__ out)
{
    int n0 = blockIdx.x * 128;
    int m0 = blockIdx.y * 128;
    int wv = threadIdx.x >> 6, l = threadIdx.x & 63;
    int l15 = l & 15, l4 = l >> 4;

    f32x4 acc[8][2] = {};
    const __hip_bfloat16* Ap = Alog + (size_t)(m0 + l15) * KLOG + l4 * 8;
    const __hip_bfloat16* Bp = W    + (size_t)(n0 + wv * 32 + l15) * KLOG + l4 * 8;

    for (int kt = 0; kt < KLOG; kt += 32) {
        bf16x8 b0 = *(const bf16x8*)(Bp + kt);
        bf16x8 b1 = *(const bf16x8*)(Bp + (size_t)16 * KLOG + kt);
        #pragma unroll
        for (int ms = 0; ms < 8; ++ms) {
            bf16x8 a = *(const bf16x8*)(Ap + (size_t)ms * 16 * KLOG + kt);
            acc[ms][0] = MFMA(a, b0, acc[ms][0]);
            acc[ms][1] = MFMA(a, b1, acc[ms][1]);
        }
    }
    #pragma unroll
    for (int ms = 0; ms < 8; ++ms)
        #pragma unroll
        for (int ns = 0; ns < 2; ++ns) {
            int col = n0 + wv * 32 + ns * 16 + l15;
            if (col < VOC) {
                float bias = bout[col];
                #pragma unroll
                for (int r = 0; r < 4; ++r) {
                    int m = m0 + ms * 16 + l4 * 4 + r;
                    int b = m & 31, t = m >> 5;
                    out[((size_t)b * TT + t) * VOC + col] = acc[ms][ns][r] + bias;
                }
            }
        }
}

// ---------------- host ----------------
extern "C" void kernel_launch(void* const* d_in, const int* in_sizes, int n_in,
                              void* d_out, int out_size, void* d_ws, size_t ws_size,
                              hipStream_t stream)
{
    (void)in_sizes; (void)n_in; (void)out_size; (void)ws_size;
    const int*   dec  = (const int*)  d_in[0];
    const float* enc  = (const float*)d_in[2];
    const float* keys = (const float*)d_in[3];
    const float* vals = (const float*)d_in[4];
    const float* emb  = (const float*)d_in[5];
    const float* Wih1 = (const float*)d_in[6];
    const float* Whh1 = (const float*)d_in[7];
    const float* b1   = (const float*)d_in[8];
    const float* Wih2 = (const float*)d_in[9];
    const float* Whh2 = (const float*)d_in[10];
    const float* b2   = (const float*)d_in[11];
    const float* Wq   = (const float*)d_in[12];
    const float* bq   = (const float*)d_in[13];
    const float* Wout = (const float*)d_in[14];
    const float* bout = (const float*)d_in[15];
    float* out = (float*)d_out;

    // workspace carve (~52 MB)
    char* p = (char*)d_ws;
    __hip_bfloat16* WoutP = (__hip_bfloat16*)p; p += (size_t)VOCP * KLOG * 2;          // 18.6 MB
    __hip_bfloat16* Alog  = (__hip_bfloat16*)p; p += (size_t)TT * BB * KLOG * 2;       // 9.4 MB
    __hip_bfloat16* Aemb  = (__hip_bfloat16*)p; p += (size_t)TT * BB * EE * 2;         // 4.2 MB
    __hip_bfloat16* H1s   = (__hip_bfloat16*)p; p += (size_t)(TT + 1) * BB * HH * 2;   // 8.45 MB
    __hip_bfloat16* H2s   = (__hip_bfloat16*)p; p += (size_t)(TT + 1) * BB * HH * 2;   // 8.45 MB
    float* PARTs = (float*)p; p += (size_t)(TT + 1) * BB * 128 * 4;                    // 2.1 MB
    int* bar = (int*)p; p += 4096;

    pack_wout  <<<dim3((KLOG + 255) / 256, VOCP), 256, 0, stream>>>(Wout, WoutP);
    init_state <<<dim3(128), 256, 0, stream>>>(enc, H1s, H2s, bar);
    gather_emb <<<dim3(TT * BB), 256, 0, stream>>>(dec, emb, Aemb);

    decoder_persistent<<<dim3(NB2), 512, KK * SS * 2 + SS * VV * 2, stream>>>(
        Wih1, Whh1, b1, Wih2, Whh2, b2, Wq, bq, keys, vals,
        Aemb, H1s, H2s, PARTs, Alog, bar);

    logits_gemm<<<dim3(VOCP / 128, (BB * TT) / 128), 256, 0, stream>>>(Alog, WoutP, bout, out);
}